// Round 5
// baseline (288.759 us; speedup 1.0000x reference)
//
#include <hip/hip_runtime.h>
#include <hip/hip_bf16.h>
#include <stdint.h>

typedef __attribute__((ext_vector_type(8))) __bf16 bf16x8;
typedef __attribute__((ext_vector_type(4))) float f32x4_t;
typedef __attribute__((ext_vector_type(2))) unsigned int u32x2;
typedef __attribute__((ext_vector_type(4))) unsigned int u32x4;
typedef unsigned int uint32;

#define EPSC 1e-6f

__device__ __forceinline__ unsigned short f2bf(float x){
  return __builtin_bit_cast(unsigned short, (__bf16)x);
}
__device__ __forceinline__ uint32 pk2(float a, float b){
  return (uint32)f2bf(a) | ((uint32)f2bf(b) << 16);
}

// ---------------- prep: WT[f][c] = bf16(W[c][f]) ----------------
__global__ void prep_wt(const float* __restrict__ W, unsigned short* __restrict__ WT){
  int c = blockIdx.x;   // 0..255
  int f = threadIdx.x;  // 0..255
  WT[(size_t)f*256 + c] = f2bf(W[(size_t)c*256 + f]);
}

// ---------------- hdeg: streaming H pass -> Hb bf16, row-sum partials, col-sum partials ----------------
// grid 1024 = (rb 0..255) x (cb 0..3); block 256 thr; block covers rows rb*64..+63, cols cb*1024..+1023
__global__ __launch_bounds__(256, 4)
void hdeg_kernel(const float* __restrict__ H, float* __restrict__ dvpart,
                 float* __restrict__ departial, unsigned short* __restrict__ Hb){
  __shared__ float wavepart[64][4];
  const int t = threadIdx.x;
  const int lane = t & 63;
  const int w = t >> 6;
  const int rb = blockIdx.x & 255;
  const int cb = blockIdx.x >> 8;
  const size_t colbase = (size_t)cb*1024 + t*4;
  f32x4_t dacc = {0.f, 0.f, 0.f, 0.f};
  #pragma unroll 4
  for (int r = 0; r < 64; ++r){
    const int n = rb*64 + r;
    f32x4_t v = *(const f32x4_t*)(H + (size_t)n*4096 + colbase);
    dacc[0] += v[0]; dacc[1] += v[1]; dacc[2] += v[2]; dacc[3] += v[3];
    *(u32x2*)(Hb + (size_t)n*4096 + colbase) = u32x2{pk2(v[0], v[1]), pk2(v[2], v[3])};
    float rs = (v[0] + v[1]) + (v[2] + v[3]);
    #pragma unroll
    for (int d = 1; d < 64; d <<= 1) rs += __shfl_xor(rs, d);
    if (lane == 0) wavepart[r][w] = rs;
  }
  *(f32x4_t*)(departial + (size_t)rb*4096 + cb*1024 + t*4) = dacc;
  __syncthreads();
  if (t < 64){
    float s = wavepart[t][0] + wavepart[t][1] + wavepart[t][2] + wavepart[t][3];
    dvpart[(size_t)cb*16384 + rb*64 + t] = s;
  }
}

// ---------------- fin_dvs: dvs[n] = rsqrt(sum_cb dvpart + eps); grid 64 ----------------
__global__ void fin_dvs(const float* __restrict__ dvpart, float* __restrict__ dvs){
  int n = blockIdx.x*256 + threadIdx.x;
  float s = dvpart[n] + dvpart[16384 + n] + dvpart[2*16384 + n] + dvpart[3*16384 + n];
  dvs[n] = rsqrtf(s + EPSC);
}

// ---------------- reduce_de: de[c] = sum_rb departial[rb][c]; grid 64 ----------------
__global__ void reduce_de(const float* __restrict__ departial, float* __restrict__ de){
  __shared__ float sm[4][64];
  int t = threadIdx.x;
  int c = blockIdx.x*64 + (t & 63);
  int part = t >> 6;
  float s = 0.f;
  #pragma unroll 4
  for (int rb = part*64; rb < part*64 + 64; ++rb)
    s += departial[(size_t)rb*4096 + c];
  sm[part][t & 63] = s;
  __syncthreads();
  if (t < 64) de[blockIdx.x*64 + t] = sm[0][t] + sm[1][t] + sm[2][t] + sm[3][t];
}

// ---------------- unified MFMA GEMM, BM=64 x BN=256, BK=32, 256 thr, dbuf ----------------
// C[M,256] = A[M,K] @ BT[256,K]^T. BT bf16 via global_load_lds (XOR-swizzled source).
// TRANS=0,ABF16=0: A f32 row-major, reg-staged f32->bf16.
// TRANS=0,ABF16=1: A bf16 row-major via global_load_lds (pre-swizzled source).
// TRANS=1,ABF16=1: A-logical = Asrc^T (Asrc bf16 [K][M]); shuffle-transpose staging.
// EPI=0: f32 partial store to Cpart + s*(NMT*64)*256 (split-K).
// EPI=1: dvs-scale rows, bf16 store transposed to XsT[f][n] (stride 16384).
// EPI=2: out[n][f] = relu(dvs[n]*acc), f32 store to Cpart (d_out).
template<int TRANS, int ABF16, int EPI, int LDA, int KB, int NMT, int CHUNK>
__global__ __launch_bounds__(256, 2)
void gemm_k(const void* __restrict__ Asrc, const unsigned short* __restrict__ BT,
            float* __restrict__ Cpart, const float* __restrict__ dvs, unsigned short* __restrict__ XsT)
{
  constexpr bool GLA = (TRANS == 0 && ABF16 == 1);
  constexpr int NIT = CHUNK / 32;
  constexpr int ASZ = 64*32*2;     // 4096 B per A buffer
  constexpr int BSZ = 256*32*2;    // 16384 B per B buffer
  __shared__ __align__(16) char lds[2*ASZ + 2*BSZ];

  const float* Af = (const float*)Asrc;
  const unsigned short* Ah = (const unsigned short*)Asrc;

  const int t = threadIdx.x;
  const int lane = t & 63;
  const int w = t >> 6;            // 0..3 (wave = one 64-col slice of F)
  const int mt = blockIdx.x % NMT;
  const int s  = blockIdx.x / NMT;
  const int k0 = s * CHUNK;

  const int st_r  = t >> 2, st_cq = t & 3;     // f32 straight staging
  const int tr_nl = t >> 3, tr_q  = t & 7;     // bf16 trans staging: n 0..31, e-octet 0..7

  f32x4_t acc[4][4] = {};
  f32x4_t pa[2];
  u32x4  paw;

  auto loadA = [&](int it){
    if (TRANS == 0 && !ABF16){
      const float* p = Af + (size_t)(mt*64 + st_r)*LDA + k0 + it*32 + st_cq*4;
      pa[0] = *(const f32x4_t*)(p);
      pa[1] = *(const f32x4_t*)(p + 16);
    } else if (TRANS == 1){
      paw = *(const u32x4*)(Ah + (size_t)(k0 + it*32 + tr_nl)*LDA + mt*64 + tr_q*8);
    }
  };

  auto gllA = [&](int it, int buf){   // TRANS=0, bf16 A via global_load_lds
    char* ab = lds + buf*ASZ;
    const int kcur = k0 + it*32;
    const int arow = lane >> 2;
    const int kqs  = (lane & 3) ^ ((lane >> 2) & 3);
    const unsigned short* src = Ah + (size_t)(mt*64 + w*16 + arow)*LDA + kcur + kqs*8;
    __builtin_amdgcn_global_load_lds((const __attribute__((address_space(1))) void*)src,
                                     (__attribute__((address_space(3))) void*)(ab + w*1024),
                                     16, 0, 0);
  };

  auto gllB = [&](int it, int buf){
    char* bb = lds + 2*ASZ + buf*BSZ;
    const int kcur = k0 + it*32;
    const int swzh = ((lane & 3) ^ ((lane >> 2) & 3)) << 3;
    #pragma unroll
    for (int j = 0; j < 4; ++j){
      int chunk = w*4 + j;
      int frow = chunk*16 + (lane >> 2);
      const unsigned short* src = BT + (size_t)frow*KB + kcur + swzh;
      __builtin_amdgcn_global_load_lds((const __attribute__((address_space(1))) void*)src,
                                       (__attribute__((address_space(3))) void*)(bb + chunk*1024),
                                       16, 0, 0);
    }
  };

  auto stageA = [&](int buf){
    char* ab = lds + buf*ASZ;
    if (TRANS == 0 && !ABF16){
      #pragma unroll
      for (int i = 0; i < 2; ++i){
        int f4 = st_cq + 4*i;
        uint32 lo = pk2(pa[i][0], pa[i][1]);
        uint32 hi = pk2(pa[i][2], pa[i][3]);
        *(u32x2*)(ab + st_r*64 + ((f4*8) ^ ((st_r & 3) << 4))) = u32x2{lo, hi};
      }
    } else if (TRANS == 1){
      const bool odd = tr_nl & 1;
      const int np = t >> 4;
      uint32 pw[4];
      #pragma unroll
      for (int j = 0; j < 4; ++j) pw[j] = (uint32)__shfl_xor((int)paw[j], 8);
      #pragma unroll
      for (int j = 0; j < 4; ++j){
        int e = tr_q*8 + 2*j + (odd ? 1 : 0);
        uint32 word = odd ? ((pw[j] >> 16)      | (paw[j] & 0xFFFF0000u))
                          : ((paw[j] & 0xFFFFu) | (pw[j] << 16));
        *(uint32*)(ab + e*64 + ((np*4) ^ ((e & 3) << 4))) = word;
      }
    }
  };

  auto compute = [&](int buf){
    const char* ab = lds + buf*ASZ;
    const char* bb = lds + 2*ASZ + buf*BSZ;
    const int kswz = (((lane >> 4) ^ (lane & 3)) << 4);
    bf16x8 af[4], bfr[4];
    #pragma unroll
    for (int mi = 0; mi < 4; ++mi){
      int row = mi*16 + (lane & 15);
      af[mi] = *(const bf16x8*)(ab + row*64 + kswz);
    }
    #pragma unroll
    for (int fi = 0; fi < 4; ++fi){
      int row = w*64 + fi*16 + (lane & 15);
      bfr[fi] = *(const bf16x8*)(bb + row*64 + kswz);
    }
    #pragma unroll
    for (int mi = 0; mi < 4; ++mi){
      #pragma unroll
      for (int fi = 0; fi < 4; ++fi){
        acc[mi][fi] = __builtin_amdgcn_mfma_f32_16x16x32_bf16(af[mi], bfr[fi], acc[mi][fi], 0, 0, 0);
      }
    }
  };

  // prologue
  if (!GLA) loadA(0);
  gllB(0, 0);
  if (GLA) gllA(0, 0); else stageA(0);
  __syncthreads();

  int cur = 0;
  #pragma unroll 1
  for (int it = 0; it < NIT; ++it){
    if (it + 1 < NIT){
      if (!GLA) loadA(it + 1);
      gllB(it + 1, cur ^ 1);
      if (GLA) gllA(it + 1, cur ^ 1);
    }
    compute(cur);
    if (it + 1 < NIT && !GLA) stageA(cur ^ 1);
    __syncthreads();
    cur ^= 1;
  }

  // epilogue
  if (EPI == 0){
    float* C = Cpart + (size_t)s * (NMT*64) * 256;
    #pragma unroll
    for (int mi = 0; mi < 4; ++mi){
      int row0 = mt*64 + mi*16 + ((lane >> 4) * 4);
      #pragma unroll
      for (int fi = 0; fi < 4; ++fi){
        int f = w*64 + fi*16 + (lane & 15);
        #pragma unroll
        for (int r = 0; r < 4; ++r)
          C[(size_t)(row0 + r)*256 + f] = acc[mi][fi][r];
      }
    }
  } else if (EPI == 1){
    #pragma unroll
    for (int mi = 0; mi < 4; ++mi){
      int n0 = mt*64 + mi*16 + ((lane >> 4) * 4);
      float d0 = dvs[n0], d1 = dvs[n0+1], d2 = dvs[n0+2], d3 = dvs[n0+3];
      #pragma unroll
      for (int fi = 0; fi < 4; ++fi){
        int f = w*64 + fi*16 + (lane & 15);
        uint32 lo = pk2(acc[mi][fi][0]*d0, acc[mi][fi][1]*d1);
        uint32 hi = pk2(acc[mi][fi][2]*d2, acc[mi][fi][3]*d3);
        *(u32x2*)(XsT + (size_t)f*16384 + n0) = u32x2{lo, hi};
      }
    }
  } else {
    #pragma unroll
    for (int mi = 0; mi < 4; ++mi){
      int n0 = mt*64 + mi*16 + ((lane >> 4) * 4);
      float d0 = dvs[n0], d1 = dvs[n0+1], d2 = dvs[n0+2], d3 = dvs[n0+3];
      #pragma unroll
      for (int fi = 0; fi < 4; ++fi){
        int f = w*64 + fi*16 + (lane & 15);
        Cpart[(size_t)(n0    )*256 + f] = fmaxf(acc[mi][fi][0]*d0, 0.f);
        Cpart[(size_t)(n0 + 1)*256 + f] = fmaxf(acc[mi][fi][1]*d1, 0.f);
        Cpart[(size_t)(n0 + 2)*256 + f] = fmaxf(acc[mi][fi][2]*d2, 0.f);
        Cpart[(size_t)(n0 + 3)*256 + f] = fmaxf(acc[mi][fi][3]*d3, 0.f);
      }
    }
  }
}

// ---------------- mid: T1sT[f][e] = bf16( (sum_s T1part[s][e][f]) / (de[e]+eps) ) ----------------
__global__ void mid_kernel(const float* __restrict__ T1part, const float* __restrict__ de,
                           unsigned short* __restrict__ T1sT){
  int f = threadIdx.x;
  int e0 = blockIdx.x * 4;
  float v[4];
  #pragma unroll
  for (int r = 0; r < 4; ++r){
    float acc = 0.f;
    #pragma unroll
    for (int s = 0; s < 8; ++s)
      acc += T1part[(size_t)s*4096*256 + (size_t)(e0 + r)*256 + f];
    v[r] = acc / (de[e0 + r] + EPSC);
  }
  uint32 lo = pk2(v[0], v[1]);
  uint32 hi = pk2(v[2], v[3]);
  *(u32x2*)(T1sT + (size_t)f*4096 + e0) = u32x2{lo, hi};
}

extern "C" void kernel_launch(void* const* d_in, const int* in_sizes, int n_in,
                              void* d_out, int out_size, void* d_ws, size_t ws_size,
                              hipStream_t stream) {
  const float* emb = (const float*)d_in[0];   // [16384,256]
  const float* H   = (const float*)d_in[1];   // [16384,4096]
  const float* W   = (const float*)d_in[2];   // [256,256]
  float* out = (float*)d_out;                 // f32 [16384,256]

  char* ws = (char*)d_ws;
  float*          dvs       = (float*)(ws + 0);                  //   65536 B
  float*          de        = (float*)(ws + 65536);              //   16384 B
  unsigned short* WT        = (unsigned short*)(ws + 81920);     //  131072 B
  unsigned short* XsT       = (unsigned short*)(ws + 212992);    // 8388608 B  [256][16384] bf16
  unsigned short* T1sT      = (unsigned short*)(ws + 8601600);   // 2097152 B  [256][4096] bf16
  unsigned short* Hb        = (unsigned short*)(ws + 10698752);  // 134217728 B [16384][4096] bf16
  float*          T1part    = (float*)(ws + 144916480);          // 33554432 B [8][4096][256]
  float*          departial = (float*)(ws + 178470912);          // 4194304 B [256][4096]
  float*          dvpart    = (float*)(ws + 182665216);          // 262144 B [4][16384]
  // total ws usage: 182,927,360 B

  prep_wt<<<256, 256, 0, stream>>>(W, WT);

  // single streaming pass over H: Hb + degree partials
  hdeg_kernel<<<1024, 256, 0, stream>>>(H, dvpart, departial, Hb);
  fin_dvs<<<64, 256, 0, stream>>>(dvpart, dvs);
  reduce_de<<<64, 256, 0, stream>>>(departial, de);

  // X: XsT[f][n] = bf16(dvs[n] * (emb@W)[n][f]);  M=16384, K=256, split-K=1
  gemm_k<0, 0, 1, 256, 256, 256, 256><<<256, 256, 0, stream>>>(emb, WT, nullptr, dvs, XsT);

  // GEMM1: T1part[s][e][f] = sum_{n in chunk s} Hb[n][e]*Xs[n][f];  M=4096 (e), K=16384 (n), split-K=8
  gemm_k<1, 1, 0, 4096, 16384, 64, 2048><<<512, 256, 0, stream>>>(Hb, XsT, T1part, nullptr, nullptr);

  // T1s = De^-1 * sum(T1part), bf16 transposed
  mid_kernel<<<1024, 256, 0, stream>>>(T1part, de, T1sT);

  // GEMM2 fused: out[n][f] = relu(dvs[n] * sum_e Hb[n][e]*T1s[e][f]);  M=16384, K=4096, split-K=1
  gemm_k<0, 1, 2, 4096, 4096, 256, 4096><<<256, 256, 0, stream>>>(Hb, T1sT, out, dvs, nullptr);
}

// Round 6
// 262.215 us; speedup vs baseline: 1.1012x; 1.1012x over previous
//
#include <hip/hip_runtime.h>
#include <hip/hip_bf16.h>
#include <stdint.h>

typedef __attribute__((ext_vector_type(8))) __bf16 bf16x8;
typedef __attribute__((ext_vector_type(4))) float f32x4_t;
typedef __attribute__((ext_vector_type(2))) unsigned int u32x2;
typedef __attribute__((ext_vector_type(4))) unsigned int u32x4;
typedef unsigned int uint32;

#define EPSC 1e-6f

__device__ __forceinline__ unsigned short f2bf(float x){
  return __builtin_bit_cast(unsigned short, (__bf16)x);
}
__device__ __forceinline__ uint32 pk2(float a, float b){
  return (uint32)f2bf(a) | ((uint32)f2bf(b) << 16);
}

// ---------------- prep: WT[f][c] = bf16(W[c][f]) ----------------
__global__ void prep_wt(const float* __restrict__ W, unsigned short* __restrict__ WT){
  int c = blockIdx.x;
  int f = threadIdx.x;
  WT[(size_t)f*256 + c] = f2bf(W[(size_t)c*256 + f]);
}

// ---------------- hdeg: streaming H pass -> Hb bf16, row-sum partials, col-sum partials ----------------
__global__ __launch_bounds__(256, 4)
void hdeg_kernel(const float* __restrict__ H, float* __restrict__ dvpart,
                 float* __restrict__ departial, unsigned short* __restrict__ Hb){
  __shared__ float wavepart[64][4];
  const int t = threadIdx.x;
  const int lane = t & 63;
  const int w = t >> 6;
  const int rb = blockIdx.x & 255;
  const int cb = blockIdx.x >> 8;
  const size_t colbase = (size_t)cb*1024 + t*4;
  f32x4_t dacc = {0.f, 0.f, 0.f, 0.f};
  #pragma unroll 4
  for (int r = 0; r < 64; ++r){
    const int n = rb*64 + r;
    f32x4_t v = *(const f32x4_t*)(H + (size_t)n*4096 + colbase);
    dacc[0] += v[0]; dacc[1] += v[1]; dacc[2] += v[2]; dacc[3] += v[3];
    *(u32x2*)(Hb + (size_t)n*4096 + colbase) = u32x2{pk2(v[0], v[1]), pk2(v[2], v[3])};
    float rs = (v[0] + v[1]) + (v[2] + v[3]);
    #pragma unroll
    for (int d = 1; d < 64; d <<= 1) rs += __shfl_xor(rs, d);
    if (lane == 0) wavepart[r][w] = rs;
  }
  *(f32x4_t*)(departial + (size_t)rb*4096 + cb*1024 + t*4) = dacc;
  __syncthreads();
  if (t < 64){
    float s = wavepart[t][0] + wavepart[t][1] + wavepart[t][2] + wavepart[t][3];
    dvpart[(size_t)cb*16384 + rb*64 + t] = s;
  }
}

// ---------------- fin_dvs ----------------
__global__ void fin_dvs(const float* __restrict__ dvpart, float* __restrict__ dvs){
  int n = blockIdx.x*256 + threadIdx.x;
  float s = dvpart[n] + dvpart[16384 + n] + dvpart[2*16384 + n] + dvpart[3*16384 + n];
  dvs[n] = rsqrtf(s + EPSC);
}

// ---------------- reduce_de ----------------
__global__ void reduce_de(const float* __restrict__ departial, float* __restrict__ de){
  __shared__ float sm[4][64];
  int t = threadIdx.x;
  int c = blockIdx.x*64 + (t & 63);
  int part = t >> 6;
  float s = 0.f;
  #pragma unroll 4
  for (int rb = part*64; rb < part*64 + 64; ++rb)
    s += departial[(size_t)rb*4096 + c];
  sm[part][t & 63] = s;
  __syncthreads();
  if (t < 64) de[blockIdx.x*64 + t] = sm[0][t] + sm[1][t] + sm[2][t] + sm[3][t];
}

// ---------------- small MFMA GEMM (X = emb@W path), verified ----------------
template<int LDA, int KB, int NMT, int CHUNK>
__global__ __launch_bounds__(256, 2)
void gemm_x(const float* __restrict__ Af, const unsigned short* __restrict__ BT,
            const float* __restrict__ dvs, unsigned short* __restrict__ XsT)
{
  constexpr int NIT = CHUNK / 32;
  constexpr int ASZ = 64*32*2;
  constexpr int BSZ = 256*32*2;
  __shared__ __align__(16) char lds[2*ASZ + 2*BSZ];

  const int t = threadIdx.x;
  const int lane = t & 63;
  const int w = t >> 6;
  const int mt = blockIdx.x % NMT;
  const int s  = blockIdx.x / NMT;
  const int k0 = s * CHUNK;

  const int st_r  = t >> 2, st_cq = t & 3;

  f32x4_t acc[4][4] = {};
  f32x4_t pa[2];

  auto loadA = [&](int it){
    const float* p = Af + (size_t)(mt*64 + st_r)*LDA + k0 + it*32 + st_cq*4;
    pa[0] = *(const f32x4_t*)(p);
    pa[1] = *(const f32x4_t*)(p + 16);
  };

  auto gllB = [&](int it, int buf){
    char* bb = lds + 2*ASZ + buf*BSZ;
    const int kcur = k0 + it*32;
    const int swzh = ((lane & 3) ^ ((lane >> 2) & 3)) << 3;
    #pragma unroll
    for (int j = 0; j < 4; ++j){
      int chunk = w*4 + j;
      int frow = chunk*16 + (lane >> 2);
      const unsigned short* src = BT + (size_t)frow*KB + kcur + swzh;
      __builtin_amdgcn_global_load_lds((const __attribute__((address_space(1))) void*)src,
                                       (__attribute__((address_space(3))) void*)(bb + chunk*1024),
                                       16, 0, 0);
    }
  };

  auto stageA = [&](int buf){
    char* ab = lds + buf*ASZ;
    #pragma unroll
    for (int i = 0; i < 2; ++i){
      int f4 = st_cq + 4*i;
      uint32 lo = pk2(pa[i][0], pa[i][1]);
      uint32 hi = pk2(pa[i][2], pa[i][3]);
      *(u32x2*)(ab + st_r*64 + ((f4*8) ^ ((st_r & 3) << 4))) = u32x2{lo, hi};
    }
  };

  auto compute = [&](int buf){
    const char* ab = lds + buf*ASZ;
    const char* bb = lds + 2*ASZ + buf*BSZ;
    const int kswz = (((lane >> 4) ^ (lane & 3)) << 4);
    bf16x8 af[4], bfr[4];
    #pragma unroll
    for (int mi = 0; mi < 4; ++mi){
      int row = mi*16 + (lane & 15);
      af[mi] = *(const bf16x8*)(ab + row*64 + kswz);
    }
    #pragma unroll
    for (int fi = 0; fi < 4; ++fi){
      int row = w*64 + fi*16 + (lane & 15);
      bfr[fi] = *(const bf16x8*)(bb + row*64 + kswz);
    }
    #pragma unroll
    for (int mi = 0; mi < 4; ++mi){
      #pragma unroll
      for (int fi = 0; fi < 4; ++fi){
        acc[mi][fi] = __builtin_amdgcn_mfma_f32_16x16x32_bf16(af[mi], bfr[fi], acc[mi][fi], 0, 0, 0);
      }
    }
  };

  loadA(0);
  gllB(0, 0);
  stageA(0);
  __syncthreads();

  int cur = 0;
  #pragma unroll 1
  for (int it = 0; it < NIT; ++it){
    if (it + 1 < NIT){
      loadA(it + 1);
      gllB(it + 1, cur ^ 1);
    }
    compute(cur);
    if (it + 1 < NIT) stageA(cur ^ 1);
    __syncthreads();
    cur ^= 1;
  }

  #pragma unroll
  for (int mi = 0; mi < 4; ++mi){
    int n0 = mt*64 + mi*16 + ((lane >> 4) * 4);
    float d0 = dvs[n0], d1 = dvs[n0+1], d2 = dvs[n0+2], d3 = dvs[n0+3];
    #pragma unroll
    for (int fi = 0; fi < 4; ++fi){
      int f = w*64 + fi*16 + (lane & 15);
      uint32 lo = pk2(acc[mi][fi][0]*d0, acc[mi][fi][1]*d1);
      uint32 hi = pk2(acc[mi][fi][2]*d2, acc[mi][fi][3]*d3);
      *(u32x2*)(XsT + (size_t)f*16384 + n0) = u32x2{lo, hi};
    }
  }
}

// ---------------- GEMM1: big MFMA GEMM BM=128 x BN=256, BK=32, 512 thr (round-4 verified) ----------------
// TRANS=1: A-logical = Asrc^T (Asrc bf16 [K][M]); shuffle-transpose staging, pq = (np>>2)^((e>>3)&3).
template<int TRANS, int LDA, int KB, int NMT, int CHUNK>
__global__ __launch_bounds__(512, 1)
void gemm_h(const unsigned short* __restrict__ Ah, const unsigned short* __restrict__ BT,
            float* __restrict__ Cpart)
{
  constexpr int NIT = CHUNK / 32;
  constexpr int ASZ = 128*32*2;
  constexpr int BSZ = 256*32*2;
  __shared__ __align__(16) char lds[2*ASZ + 2*BSZ];

  const int t = threadIdx.x;
  const int lane = t & 63;
  const int w = t >> 6;
  const int wm = w >> 2;
  const int wf = w & 3;
  const int mt = blockIdx.x % NMT;
  const int s  = blockIdx.x / NMT;
  const int k0 = s * CHUNK;

  f32x4_t acc[4][4] = {};
  u32x4 paw;

  auto gllB = [&](int it, int buf){
    char* bb = lds + 2*ASZ + buf*BSZ;
    const int kcur = k0 + it*32;
    const int swzh = ((lane & 3) ^ ((lane >> 2) & 3)) << 3;
    #pragma unroll
    for (int j = 0; j < 2; ++j){
      int chunk = w*2 + j;
      int frow = chunk*16 + (lane >> 2);
      const unsigned short* src = BT + (size_t)frow*KB + kcur + swzh;
      __builtin_amdgcn_global_load_lds((const __attribute__((address_space(1))) void*)src,
                                       (__attribute__((address_space(3))) void*)(bb + chunk*1024),
                                       16, 0, 0);
    }
  };

  auto gllA = [&](int it, int buf){   // TRANS=0
    char* ab = lds + buf*ASZ;
    const int kcur = k0 + it*32;
    const int arow = lane >> 2;
    const int kqs  = (lane & 3) ^ (arow & 3);
    const unsigned short* src = Ah + (size_t)(mt*128 + w*16 + arow)*LDA + kcur + kqs*8;
    __builtin_amdgcn_global_load_lds((const __attribute__((address_space(1))) void*)src,
                                     (__attribute__((address_space(3))) void*)(ab + w*1024),
                                     16, 0, 0);
  };

  auto loadA_tr = [&](int it){
    paw = *(const u32x4*)(Ah + (size_t)(k0 + it*32 + (t >> 4))*LDA + mt*128 + (t & 15)*8);
  };

  auto stageA_tr = [&](int buf){
    char* ab = lds + buf*ASZ;
    const int n = t >> 4;
    const int trq = t & 15;
    const bool odd = n & 1;
    const int np = n >> 1;
    uint32 pw[4];
    #pragma unroll
    for (int j = 0; j < 4; ++j) pw[j] = (uint32)__shfl_xor((int)paw[j], 16);
    #pragma unroll
    for (int j = 0; j < 4; ++j){
      int e = trq*8 + 2*j + (odd ? 1 : 0);
      uint32 word = odd ? ((pw[j] >> 16)      | (paw[j] & 0xFFFF0000u))
                        : ((paw[j] & 0xFFFFu) | (pw[j] << 16));
      int pq = (np >> 2) ^ (trq & 3);
      *(uint32*)(ab + e*64 + pq*16 + (np & 3)*4) = word;
    }
  };

  auto compute = [&](int buf){
    const char* ab = lds + buf*ASZ;
    const char* bb = lds + 2*ASZ + buf*BSZ;
    const int l15 = lane & 15;
    const int kq = lane >> 4;
    bf16x8 af[4], bfr[4];
    #pragma unroll
    for (int mi = 0; mi < 4; ++mi){
      int row = wm*64 + mi*16 + l15;
      int q = TRANS ? (kq ^ ((row >> 3) & 3)) : (kq ^ (row & 3));
      af[mi] = *(const bf16x8*)(ab + row*64 + q*16);
    }
    #pragma unroll
    for (int fi = 0; fi < 4; ++fi){
      int row = wf*64 + fi*16 + l15;
      bfr[fi] = *(const bf16x8*)(bb + row*64 + ((kq ^ (l15 & 3)) << 4));
    }
    #pragma unroll
    for (int mi = 0; mi < 4; ++mi){
      #pragma unroll
      for (int fi = 0; fi < 4; ++fi){
        acc[mi][fi] = __builtin_amdgcn_mfma_f32_16x16x32_bf16(af[mi], bfr[fi], acc[mi][fi], 0, 0, 0);
      }
    }
  };

  if (TRANS) loadA_tr(0);
  gllB(0, 0);
  if (TRANS) stageA_tr(0); else gllA(0, 0);
  __syncthreads();

  int cur = 0;
  #pragma unroll 1
  for (int it = 0; it < NIT; ++it){
    if (it + 1 < NIT){
      if (TRANS) loadA_tr(it + 1);
      gllB(it + 1, cur ^ 1);
      if (!TRANS) gllA(it + 1, cur ^ 1);
    }
    compute(cur);
    if (TRANS && it + 1 < NIT) stageA_tr(cur ^ 1);
    __syncthreads();
    cur ^= 1;
  }

  float* C = Cpart + (size_t)s * (NMT*128) * 256;
  #pragma unroll
  for (int mi = 0; mi < 4; ++mi){
    int row0 = mt*128 + wm*64 + mi*16 + ((lane >> 4) * 4);
    #pragma unroll
    for (int fi = 0; fi < 4; ++fi){
      int f = wf*64 + fi*16 + (lane & 15);
      #pragma unroll
      for (int r = 0; r < 4; ++r)
        C[(size_t)(row0 + r)*256 + f] = acc[mi][fi][r];
    }
  }
}

// ---------------- GEMM2 fused: out = relu(dvs .* (Hb @ T1s)), BM=64 x BN=256, 512 thr, unroll-2 K ----------------
// 8 waves (wm = w>>2 m-half of 32 rows, wf = w&3 f-quarter); 4 LDS buffer pairs; 64 barrier phases.
template<int LDA, int KB, int NMT, int K>
__global__ __launch_bounds__(512, 1)
void gemm2_fused(const unsigned short* __restrict__ Ah, const unsigned short* __restrict__ BT,
                 const float* __restrict__ dvs, float* __restrict__ out)
{
  constexpr int NIT = K / 32;      // 128
  constexpr int PH  = NIT / 2;     // 64
  constexpr int ASZ = 64*32*2;     // 4096 B
  constexpr int BSZ = 256*32*2;    // 16384 B
  __shared__ __align__(16) char lds[4*ASZ + 4*BSZ];   // 81920 B

  const int t = threadIdx.x;
  const int lane = t & 63;
  const int w = t >> 6;            // 0..7
  const int wm = w >> 2;           // 0..1
  const int wf = w & 3;            // 0..3
  const int mt = blockIdx.x;       // 0..NMT-1

  f32x4_t acc[2][4] = {};

  auto gllA = [&](int it, int buf){
    if (t < 256){
      char* ab = lds + buf*ASZ;
      const int w4 = t >> 6;                      // 0..3
      const int l = t & 63;
      const int arow = l >> 2;
      const int kqs  = (l & 3) ^ (arow & 3);
      const unsigned short* src = Ah + (size_t)(mt*64 + w4*16 + arow)*LDA + it*32 + kqs*8;
      __builtin_amdgcn_global_load_lds((const __attribute__((address_space(1))) void*)src,
                                       (__attribute__((address_space(3))) void*)(ab + w4*1024),
                                       16, 0, 0);
    }
  };

  auto gllB = [&](int it, int buf){
    char* bb = lds + 4*ASZ + buf*BSZ;
    const int kcur = it*32;
    const int swzh = ((lane & 3) ^ ((lane >> 2) & 3)) << 3;
    #pragma unroll
    for (int j = 0; j < 2; ++j){
      int chunk = w*2 + j;                        // 0..15
      int frow = chunk*16 + (lane >> 2);
      const unsigned short* src = BT + (size_t)frow*KB + kcur + swzh;
      __builtin_amdgcn_global_load_lds((const __attribute__((address_space(1))) void*)src,
                                       (__attribute__((address_space(3))) void*)(bb + chunk*1024),
                                       16, 0, 0);
    }
  };

  auto compute = [&](int buf){
    const char* ab = lds + buf*ASZ;
    const char* bb = lds + 4*ASZ + buf*BSZ;
    const int kswz = (((lane >> 4) ^ (lane & 3)) << 4);
    bf16x8 af[2], bfr[4];
    #pragma unroll
    for (int mi = 0; mi < 2; ++mi){
      int row = wm*32 + mi*16 + (lane & 15);
      af[mi] = *(const bf16x8*)(ab + row*64 + kswz);
    }
    #pragma unroll
    for (int fi = 0; fi < 4; ++fi){
      int row = wf*64 + fi*16 + (lane & 15);
      bfr[fi] = *(const bf16x8*)(bb + row*64 + kswz);
    }
    #pragma unroll
    for (int mi = 0; mi < 2; ++mi){
      #pragma unroll
      for (int fi = 0; fi < 4; ++fi){
        acc[mi][fi] = __builtin_amdgcn_mfma_f32_16x16x32_bf16(af[mi], bfr[fi], acc[mi][fi], 0, 0, 0);
      }
    }
  };

  // prologue: load iters 0,1 into buffer pair {0,1}
  gllB(0, 0); gllA(0, 0);
  gllB(1, 1); gllA(1, 1);
  __syncthreads();

  #pragma unroll 1
  for (int ph = 0; ph < PH; ++ph){
    const int cur = (ph & 1) << 1;               // 0 or 2
    if (ph + 1 < PH){
      gllB(2*ph + 2, cur ^ 2);  gllA(2*ph + 2, cur ^ 2);
      gllB(2*ph + 3, (cur ^ 2) + 1);  gllA(2*ph + 3, (cur ^ 2) + 1);
    }
    compute(cur);
    compute(cur + 1);
    __syncthreads();
  }

  // fused epilogue: relu(dvs * acc) -> f32 out
  #pragma unroll
  for (int mi = 0; mi < 2; ++mi){
    int n0 = mt*64 + wm*32 + mi*16 + ((lane >> 4) * 4);
    float d0 = dvs[n0], d1 = dvs[n0+1], d2 = dvs[n0+2], d3 = dvs[n0+3];
    #pragma unroll
    for (int fi = 0; fi < 4; ++fi){
      int f = wf*64 + fi*16 + (lane & 15);
      out[(size_t)(n0    )*256 + f] = fmaxf(acc[mi][fi][0]*d0, 0.f);
      out[(size_t)(n0 + 1)*256 + f] = fmaxf(acc[mi][fi][1]*d1, 0.f);
      out[(size_t)(n0 + 2)*256 + f] = fmaxf(acc[mi][fi][2]*d2, 0.f);
      out[(size_t)(n0 + 3)*256 + f] = fmaxf(acc[mi][fi][3]*d3, 0.f);
    }
  }
}

// ---------------- mid: T1sT[f][e] = bf16( (sum_s T1part[s][e][f]) / (de[e]+eps) ) ----------------
__global__ void mid_kernel(const float* __restrict__ T1part, const float* __restrict__ de,
                           unsigned short* __restrict__ T1sT){
  int f = threadIdx.x;
  int e0 = blockIdx.x * 4;
  float v[4];
  #pragma unroll
  for (int r = 0; r < 4; ++r){
    float acc = 0.f;
    #pragma unroll
    for (int s = 0; s < 8; ++s)
      acc += T1part[(size_t)s*4096*256 + (size_t)(e0 + r)*256 + f];
    v[r] = acc / (de[e0 + r] + EPSC);
  }
  uint32 lo = pk2(v[0], v[1]);
  uint32 hi = pk2(v[2], v[3]);
  *(u32x2*)(T1sT + (size_t)f*4096 + e0) = u32x2{lo, hi};
}

extern "C" void kernel_launch(void* const* d_in, const int* in_sizes, int n_in,
                              void* d_out, int out_size, void* d_ws, size_t ws_size,
                              hipStream_t stream) {
  const float* emb = (const float*)d_in[0];   // [16384,256]
  const float* H   = (const float*)d_in[1];   // [16384,4096]
  const float* W   = (const float*)d_in[2];   // [256,256]
  float* out = (float*)d_out;                 // f32 [16384,256]

  char* ws = (char*)d_ws;
  float*          dvs       = (float*)(ws + 0);                  //   65536 B
  float*          de        = (float*)(ws + 65536);              //   16384 B
  unsigned short* WT        = (unsigned short*)(ws + 81920);     //  131072 B
  unsigned short* XsT       = (unsigned short*)(ws + 212992);    // 8388608 B  [256][16384] bf16
  unsigned short* T1sT      = (unsigned short*)(ws + 8601600);   // 2097152 B  [256][4096] bf16
  unsigned short* Hb        = (unsigned short*)(ws + 10698752);  // 134217728 B [16384][4096] bf16
  float*          T1part    = (float*)(ws + 144916480);          // 33554432 B [8][4096][256]
  float*          departial = (float*)(ws + 178470912);          // 4194304 B [256][4096]
  float*          dvpart    = (float*)(ws + 182665216);          // 262144 B [4][16384]
  // total ws usage: 182,927,360 B

  prep_wt<<<256, 256, 0, stream>>>(W, WT);

  // single streaming pass over H: Hb + degree partials
  hdeg_kernel<<<1024, 256, 0, stream>>>(H, dvpart, departial, Hb);
  fin_dvs<<<64, 256, 0, stream>>>(dvpart, dvs);
  reduce_de<<<64, 256, 0, stream>>>(departial, de);

  // X: XsT[f][n] = bf16(dvs[n] * (emb@W)[n][f]);  M=16384, K=256
  gemm_x<256, 256, 256, 256><<<256, 256, 0, stream>>>(emb, WT, dvs, XsT);

  // GEMM1: T1part[s][e][f] = sum_{n in chunk s} Hb[n][e]*Xs[n][f];  M=4096 (e), K=16384 (n), split-K=8
  gemm_h<1, 4096, 16384, 32, 2048><<<256, 512, 0, stream>>>(Hb, XsT, T1part);

  // T1s = De^-1 * sum(T1part), bf16 transposed
  mid_kernel<<<1024, 256, 0, stream>>>(T1part, de, T1sT);

  // GEMM2 fused: out[n][f] = relu(dvs[n] * sum_e Hb[n][e]*T1s[e][f]);  M=16384, K=4096
  gemm2_fused<4096, 4096, 256, 4096><<<256, 512, 0, stream>>>(Hb, T1sT, dvs, out);
}

// Round 7
// 259.078 us; speedup vs baseline: 1.1146x; 1.0121x over previous
//
#include <hip/hip_runtime.h>
#include <hip/hip_bf16.h>
#include <stdint.h>

typedef __attribute__((ext_vector_type(8))) __bf16 bf16x8;
typedef __attribute__((ext_vector_type(4))) float f32x4_t;
typedef __attribute__((ext_vector_type(2))) unsigned int u32x2;
typedef __attribute__((ext_vector_type(4))) unsigned int u32x4;
typedef unsigned int uint32;

#define EPSC 1e-6f

__device__ __forceinline__ unsigned short f2bf(float x){
  return __builtin_bit_cast(unsigned short, (__bf16)x);
}
__device__ __forceinline__ uint32 pk2(float a, float b){
  return (uint32)f2bf(a) | ((uint32)f2bf(b) << 16);
}

// ---------------- prep: WT[f][c] = bf16(W[c][f]) ----------------
__global__ void prep_wt(const float* __restrict__ W, unsigned short* __restrict__ WT){
  int c = blockIdx.x;
  int f = threadIdx.x;
  WT[(size_t)f*256 + c] = f2bf(W[(size_t)c*256 + f]);
}

// ---------------- hdeg: streaming H pass -> Hb bf16, row-sum partials, col-sum partials ----------------
// grid 1024 = (rb 0..255) x (cb 0..3); block 256 thr; block covers rows rb*64..+63, cols cb*1024..+1023
__global__ __launch_bounds__(256, 4)
void hdeg_kernel(const float* __restrict__ H, float* __restrict__ dvpart,
                 float* __restrict__ departial, unsigned short* __restrict__ Hb){
  __shared__ float wavepart[64][4];
  const int t = threadIdx.x;
  const int lane = t & 63;
  const int w = t >> 6;
  const int rb = blockIdx.x & 255;
  const int cb = blockIdx.x >> 8;
  const size_t colbase = (size_t)cb*1024 + t*4;
  f32x4_t dacc = {0.f, 0.f, 0.f, 0.f};
  #pragma unroll 4
  for (int r = 0; r < 64; ++r){
    const int n = rb*64 + r;
    f32x4_t v = *(const f32x4_t*)(H + (size_t)n*4096 + colbase);
    dacc[0] += v[0]; dacc[1] += v[1]; dacc[2] += v[2]; dacc[3] += v[3];
    *(u32x2*)(Hb + (size_t)n*4096 + colbase) = u32x2{pk2(v[0], v[1]), pk2(v[2], v[3])};
    float rs = (v[0] + v[1]) + (v[2] + v[3]);
    #pragma unroll
    for (int d = 1; d < 64; d <<= 1) rs += __shfl_xor(rs, d);
    if (lane == 0) wavepart[r][w] = rs;
  }
  *(f32x4_t*)(departial + (size_t)rb*4096 + cb*1024 + t*4) = dacc;
  __syncthreads();
  if (t < 64){
    float s = wavepart[t][0] + wavepart[t][1] + wavepart[t][2] + wavepart[t][3];
    dvpart[(size_t)cb*16384 + rb*64 + t] = s;
  }
}

// ---------------- fin_dvs ----------------
__global__ void fin_dvs(const float* __restrict__ dvpart, float* __restrict__ dvs){
  int n = blockIdx.x*256 + threadIdx.x;
  float s = dvpart[n] + dvpart[16384 + n] + dvpart[2*16384 + n] + dvpart[3*16384 + n];
  dvs[n] = rsqrtf(s + EPSC);
}

// ---------------- reduce_de ----------------
__global__ void reduce_de(const float* __restrict__ departial, float* __restrict__ de){
  __shared__ float sm[4][64];
  int t = threadIdx.x;
  int c = blockIdx.x*64 + (t & 63);
  int part = t >> 6;
  float s = 0.f;
  #pragma unroll 4
  for (int rb = part*64; rb < part*64 + 64; ++rb)
    s += departial[(size_t)rb*4096 + c];
  sm[part][t & 63] = s;
  __syncthreads();
  if (t < 64) de[blockIdx.x*64 + t] = sm[0][t] + sm[1][t] + sm[2][t] + sm[3][t];
}

// ---------------- unified MFMA GEMM, BM=64 x BN=256, BK=32, 256 thr, dbuf (round-3 verified) ----------------
// C[M,256] = A[M,K] @ BT[256,K]^T. BT bf16 via global_load_lds (XOR-swizzled source).
// TRANS=0,ABF16=0: A f32 row-major, reg-staged f32->bf16.
// TRANS=0,ABF16=1: A bf16 row-major via global_load_lds (pre-swizzled source).
// TRANS=1,ABF16=1: A-logical = Asrc^T (Asrc bf16 [K][M]); shuffle-transpose staging.
// EPI=0: f32 partial store to Cpart + s*(NMT*64)*256 (split-K).
// EPI=1: dvs-scale rows, bf16 store transposed to XsT[f][n] (stride 16384).
template<int TRANS, int ABF16, int EPI, int LDA, int KB, int NMT, int CHUNK>
__global__ __launch_bounds__(256, 2)
void gemm_k(const void* __restrict__ Asrc, const unsigned short* __restrict__ BT,
            float* __restrict__ Cpart, const float* __restrict__ dvs, unsigned short* __restrict__ XsT)
{
  constexpr bool GLA = (TRANS == 0 && ABF16 == 1);
  constexpr int NIT = CHUNK / 32;
  constexpr int ASZ = 64*32*2;     // 4096 B per A buffer
  constexpr int BSZ = 256*32*2;    // 16384 B per B buffer
  __shared__ __align__(16) char lds[2*ASZ + 2*BSZ];

  const float* Af = (const float*)Asrc;
  const unsigned short* Ah = (const unsigned short*)Asrc;

  const int t = threadIdx.x;
  const int lane = t & 63;
  const int w = t >> 6;            // 0..3 (wave = one 64-col slice of F)
  const int mt = blockIdx.x % NMT;
  const int s  = blockIdx.x / NMT;
  const int k0 = s * CHUNK;

  const int st_r  = t >> 2, st_cq = t & 3;     // f32 straight staging
  const int tr_nl = t >> 3, tr_q  = t & 7;     // bf16 trans staging: n 0..31, e-octet 0..7

  f32x4_t acc[4][4] = {};
  f32x4_t pa[2];
  u32x4  paw;

  auto loadA = [&](int it){
    if (TRANS == 0 && !ABF16){
      const float* p = Af + (size_t)(mt*64 + st_r)*LDA + k0 + it*32 + st_cq*4;
      pa[0] = *(const f32x4_t*)(p);
      pa[1] = *(const f32x4_t*)(p + 16);
    } else if (TRANS == 1){
      paw = *(const u32x4*)(Ah + (size_t)(k0 + it*32 + tr_nl)*LDA + mt*64 + tr_q*8);
    }
  };

  auto gllA = [&](int it, int buf){   // TRANS=0, bf16 A via global_load_lds
    char* ab = lds + buf*ASZ;
    const int kcur = k0 + it*32;
    const int arow = lane >> 2;
    const int kqs  = (lane & 3) ^ ((lane >> 2) & 3);
    const unsigned short* src = Ah + (size_t)(mt*64 + w*16 + arow)*LDA + kcur + kqs*8;
    __builtin_amdgcn_global_load_lds((const __attribute__((address_space(1))) void*)src,
                                     (__attribute__((address_space(3))) void*)(ab + w*1024),
                                     16, 0, 0);
  };

  auto gllB = [&](int it, int buf){
    char* bb = lds + 2*ASZ + buf*BSZ;
    const int kcur = k0 + it*32;
    const int swzh = ((lane & 3) ^ ((lane >> 2) & 3)) << 3;
    #pragma unroll
    for (int j = 0; j < 4; ++j){
      int chunk = w*4 + j;
      int frow = chunk*16 + (lane >> 2);
      const unsigned short* src = BT + (size_t)frow*KB + kcur + swzh;
      __builtin_amdgcn_global_load_lds((const __attribute__((address_space(1))) void*)src,
                                       (__attribute__((address_space(3))) void*)(bb + chunk*1024),
                                       16, 0, 0);
    }
  };

  auto stageA = [&](int buf){
    char* ab = lds + buf*ASZ;
    if (TRANS == 0 && !ABF16){
      #pragma unroll
      for (int i = 0; i < 2; ++i){
        int f4 = st_cq + 4*i;
        uint32 lo = pk2(pa[i][0], pa[i][1]);
        uint32 hi = pk2(pa[i][2], pa[i][3]);
        *(u32x2*)(ab + st_r*64 + ((f4*8) ^ ((st_r & 3) << 4))) = u32x2{lo, hi};
      }
    } else if (TRANS == 1){
      const bool odd = tr_nl & 1;
      const int np = t >> 4;
      uint32 pw[4];
      #pragma unroll
      for (int j = 0; j < 4; ++j) pw[j] = (uint32)__shfl_xor((int)paw[j], 8);
      #pragma unroll
      for (int j = 0; j < 4; ++j){
        int e = tr_q*8 + 2*j + (odd ? 1 : 0);
        uint32 word = odd ? ((pw[j] >> 16)      | (paw[j] & 0xFFFF0000u))
                          : ((paw[j] & 0xFFFFu) | (pw[j] << 16));
        *(uint32*)(ab + e*64 + ((np*4) ^ ((e & 3) << 4))) = word;
      }
    }
  };

  auto compute = [&](int buf){
    const char* ab = lds + buf*ASZ;
    const char* bb = lds + 2*ASZ + buf*BSZ;
    const int kswz = (((lane >> 4) ^ (lane & 3)) << 4);
    bf16x8 af[4], bfr[4];
    #pragma unroll
    for (int mi = 0; mi < 4; ++mi){
      int row = mi*16 + (lane & 15);
      af[mi] = *(const bf16x8*)(ab + row*64 + kswz);
    }
    #pragma unroll
    for (int fi = 0; fi < 4; ++fi){
      int row = w*64 + fi*16 + (lane & 15);
      bfr[fi] = *(const bf16x8*)(bb + row*64 + kswz);
    }
    #pragma unroll
    for (int mi = 0; mi < 4; ++mi){
      #pragma unroll
      for (int fi = 0; fi < 4; ++fi){
        acc[mi][fi] = __builtin_amdgcn_mfma_f32_16x16x32_bf16(af[mi], bfr[fi], acc[mi][fi], 0, 0, 0);
      }
    }
  };

  // prologue
  if (!GLA) loadA(0);
  gllB(0, 0);
  if (GLA) gllA(0, 0); else stageA(0);
  __syncthreads();

  int cur = 0;
  #pragma unroll 1
  for (int it = 0; it < NIT; ++it){
    if (it + 1 < NIT){
      if (!GLA) loadA(it + 1);
      gllB(it + 1, cur ^ 1);
      if (GLA) gllA(it + 1, cur ^ 1);
    }
    compute(cur);
    if (it + 1 < NIT && !GLA) stageA(cur ^ 1);
    __syncthreads();
    cur ^= 1;
  }

  // epilogue
  if (EPI == 0){
    float* C = Cpart + (size_t)s * (NMT*64) * 256;
    #pragma unroll
    for (int mi = 0; mi < 4; ++mi){
      int row0 = mt*64 + mi*16 + ((lane >> 4) * 4);
      #pragma unroll
      for (int fi = 0; fi < 4; ++fi){
        int f = w*64 + fi*16 + (lane & 15);
        #pragma unroll
        for (int r = 0; r < 4; ++r)
          C[(size_t)(row0 + r)*256 + f] = acc[mi][fi][r];
      }
    }
  } else {
    #pragma unroll
    for (int mi = 0; mi < 4; ++mi){
      int n0 = mt*64 + mi*16 + ((lane >> 4) * 4);
      float d0 = dvs[n0], d1 = dvs[n0+1], d2 = dvs[n0+2], d3 = dvs[n0+3];
      #pragma unroll
      for (int fi = 0; fi < 4; ++fi){
        int f = w*64 + fi*16 + (lane & 15);
        uint32 lo = pk2(acc[mi][fi][0]*d0, acc[mi][fi][1]*d1);
        uint32 hi = pk2(acc[mi][fi][2]*d2, acc[mi][fi][3]*d3);
        *(u32x2*)(XsT + (size_t)f*16384 + n0) = u32x2{lo, hi};
      }
    }
  }
}

// ---------------- small MFMA GEMM (X = emb@W path), round-4 verified ----------------
template<int LDA, int KB, int NMT, int CHUNK>
__global__ __launch_bounds__(256, 2)
void gemm_x(const float* __restrict__ Af, const unsigned short* __restrict__ BT,
            const float* __restrict__ dvs, unsigned short* __restrict__ XsT)
{
  constexpr int NIT = CHUNK / 32;
  constexpr int ASZ = 64*32*2;
  constexpr int BSZ = 256*32*2;
  __shared__ __align__(16) char lds[2*ASZ + 2*BSZ];

  const int t = threadIdx.x;
  const int lane = t & 63;
  const int w = t >> 6;
  const int mt = blockIdx.x % NMT;
  const int s  = blockIdx.x / NMT;
  const int k0 = s * CHUNK;

  const int st_r  = t >> 2, st_cq = t & 3;

  f32x4_t acc[4][4] = {};
  f32x4_t pa[2];

  auto loadA = [&](int it){
    const float* p = Af + (size_t)(mt*64 + st_r)*LDA + k0 + it*32 + st_cq*4;
    pa[0] = *(const f32x4_t*)(p);
    pa[1] = *(const f32x4_t*)(p + 16);
  };

  auto gllB = [&](int it, int buf){
    char* bb = lds + 2*ASZ + buf*BSZ;
    const int kcur = k0 + it*32;
    const int swzh = ((lane & 3) ^ ((lane >> 2) & 3)) << 3;
    #pragma unroll
    for (int j = 0; j < 4; ++j){
      int chunk = w*4 + j;
      int frow = chunk*16 + (lane >> 2);
      const unsigned short* src = BT + (size_t)frow*KB + kcur + swzh;
      __builtin_amdgcn_global_load_lds((const __attribute__((address_space(1))) void*)src,
                                       (__attribute__((address_space(3))) void*)(bb + chunk*1024),
                                       16, 0, 0);
    }
  };

  auto stageA = [&](int buf){
    char* ab = lds + buf*ASZ;
    #pragma unroll
    for (int i = 0; i < 2; ++i){
      int f4 = st_cq + 4*i;
      uint32 lo = pk2(pa[i][0], pa[i][1]);
      uint32 hi = pk2(pa[i][2], pa[i][3]);
      *(u32x2*)(ab + st_r*64 + ((f4*8) ^ ((st_r & 3) << 4))) = u32x2{lo, hi};
    }
  };

  auto compute = [&](int buf){
    const char* ab = lds + buf*ASZ;
    const char* bb = lds + 2*ASZ + buf*BSZ;
    const int kswz = (((lane >> 4) ^ (lane & 3)) << 4);
    bf16x8 af[4], bfr[4];
    #pragma unroll
    for (int mi = 0; mi < 4; ++mi){
      int row = mi*16 + (lane & 15);
      af[mi] = *(const bf16x8*)(ab + row*64 + kswz);
    }
    #pragma unroll
    for (int fi = 0; fi < 4; ++fi){
      int row = w*64 + fi*16 + (lane & 15);
      bfr[fi] = *(const bf16x8*)(bb + row*64 + kswz);
    }
    #pragma unroll
    for (int mi = 0; mi < 4; ++mi){
      #pragma unroll
      for (int fi = 0; fi < 4; ++fi){
        acc[mi][fi] = __builtin_amdgcn_mfma_f32_16x16x32_bf16(af[mi], bfr[fi], acc[mi][fi], 0, 0, 0);
      }
    }
  };

  loadA(0);
  gllB(0, 0);
  stageA(0);
  __syncthreads();

  int cur = 0;
  #pragma unroll 1
  for (int it = 0; it < NIT; ++it){
    if (it + 1 < NIT){
      loadA(it + 1);
      gllB(it + 1, cur ^ 1);
    }
    compute(cur);
    if (it + 1 < NIT) stageA(cur ^ 1);
    __syncthreads();
    cur ^= 1;
  }

  #pragma unroll
  for (int mi = 0; mi < 4; ++mi){
    int n0 = mt*64 + mi*16 + ((lane >> 4) * 4);
    float d0 = dvs[n0], d1 = dvs[n0+1], d2 = dvs[n0+2], d3 = dvs[n0+3];
    #pragma unroll
    for (int fi = 0; fi < 4; ++fi){
      int f = w*64 + fi*16 + (lane & 15);
      uint32 lo = pk2(acc[mi][fi][0]*d0, acc[mi][fi][1]*d1);
      uint32 hi = pk2(acc[mi][fi][2]*d2, acc[mi][fi][3]*d3);
      *(u32x2*)(XsT + (size_t)f*16384 + n0) = u32x2{lo, hi};
    }
  }
}

// ---------------- mid: T1sT[f][e] = bf16( (sum_s T1part[s][e][f]) / (de[e]+eps) ) ----------------
__global__ void mid_kernel(const float* __restrict__ T1part, const float* __restrict__ de,
                           unsigned short* __restrict__ T1sT){
  int f = threadIdx.x;
  int e0 = blockIdx.x * 4;
  float v[4];
  #pragma unroll
  for (int r = 0; r < 4; ++r){
    float acc = 0.f;
    #pragma unroll
    for (int s = 0; s < 8; ++s)
      acc += T1part[(size_t)s*4096*256 + (size_t)(e0 + r)*256 + f];
    v[r] = acc / (de[e0 + r] + EPSC);
  }
  uint32 lo = pk2(v[0], v[1]);
  uint32 hi = pk2(v[2], v[3]);
  *(u32x2*)(T1sT + (size_t)f*4096 + e0) = u32x2{lo, hi};
}

// ---------------- fin: out[n][f] = relu(dvs[n] * (P0+P1)[n][f]), f32 ----------------
__global__ void fin_kernel(const float* __restrict__ P0, const float* __restrict__ P1,
                           const float* __restrict__ dvs, float* __restrict__ out){
  int gid = blockIdx.x*256 + threadIdx.x;
  int n = gid >> 5;
  int f0 = (gid & 31) * 8;
  size_t off = (size_t)n*256 + f0;
  f32x4_t a0 = *(const f32x4_t*)(P0 + off);
  f32x4_t a1 = *(const f32x4_t*)(P0 + off + 4);
  f32x4_t b0 = *(const f32x4_t*)(P1 + off);
  f32x4_t b1 = *(const f32x4_t*)(P1 + off + 4);
  float d = dvs[n];
  f32x4_t oa, ob;
  #pragma unroll
  for (int j = 0; j < 4; ++j){
    oa[j] = fmaxf((a0[j] + b0[j]) * d, 0.f);
    ob[j] = fmaxf((a1[j] + b1[j]) * d, 0.f);
  }
  *(f32x4_t*)(out + off) = oa;
  *(f32x4_t*)(out + off + 4) = ob;
}

extern "C" void kernel_launch(void* const* d_in, const int* in_sizes, int n_in,
                              void* d_out, int out_size, void* d_ws, size_t ws_size,
                              hipStream_t stream) {
  const float* emb = (const float*)d_in[0];   // [16384,256]
  const float* H   = (const float*)d_in[1];   // [16384,4096]
  const float* W   = (const float*)d_in[2];   // [256,256]
  float* out = (float*)d_out;                 // f32 [16384,256]

  char* ws = (char*)d_ws;
  float*          dvs       = (float*)(ws + 0);                  //   65536 B
  float*          de        = (float*)(ws + 65536);              //   16384 B
  unsigned short* WT        = (unsigned short*)(ws + 81920);     //  131072 B
  unsigned short* XsT       = (unsigned short*)(ws + 212992);    // 8388608 B  [256][16384] bf16
  unsigned short* T1sT      = (unsigned short*)(ws + 8601600);   // 2097152 B  [256][4096] bf16
  unsigned short* Hb        = (unsigned short*)(ws + 10698752);  // 134217728 B [16384][4096] bf16
  float*          T1part    = (float*)(ws + 144916480);          // 33554432 B [8][4096][256]
  float*          Opart     = (float*)(ws + 178470912);          // 33554432 B [2][16384][256]
  float*          departial = (float*)(ws + 212025344);          // 4194304 B [256][4096]
  float*          dvpart    = (float*)(ws + 216219648);          // 262144 B [4][16384]
  // total ws usage: 216,481,792 B

  prep_wt<<<256, 256, 0, stream>>>(W, WT);

  // single streaming pass over H: Hb + degree partials
  hdeg_kernel<<<1024, 256, 0, stream>>>(H, dvpart, departial, Hb);
  fin_dvs<<<64, 256, 0, stream>>>(dvpart, dvs);
  reduce_de<<<64, 256, 0, stream>>>(departial, de);

  // X: XsT[f][n] = bf16(dvs[n] * (emb@W)[n][f]);  M=16384, K=256
  gemm_x<256, 256, 256, 256><<<256, 256, 0, stream>>>(emb, WT, dvs, XsT);

  // GEMM1: T1part[s][e][f] = sum_{n in chunk s} Hb[n][e]*Xs[n][f];  M=4096 (e), K=16384 (n), split-K=8
  gemm_k<1, 1, 0, 4096, 16384, 64, 2048><<<512, 256, 0, stream>>>(Hb, XsT, T1part, nullptr, nullptr);

  // T1s = De^-1 * sum(T1part), bf16 transposed
  mid_kernel<<<1024, 256, 0, stream>>>(T1part, de, T1sT);

  // GEMM2: Opart[s][n][f] = sum_{e in chunk s} Hb[n][e]*T1s[e][f];  M=16384 (n), K=4096 (e), split-K=2
  gemm_k<0, 1, 0, 4096, 4096, 256, 2048><<<512, 256, 0, stream>>>(Hb, T1sT, Opart, nullptr, nullptr);

  // out = relu(dvs[n] * (Opart0 + Opart1))
  fin_kernel<<<2048, 256, 0, stream>>>(Opart, Opart + (size_t)16384*256, dvs, out);
}

// Round 8
// 241.640 us; speedup vs baseline: 1.1950x; 1.0722x over previous
//
#include <hip/hip_runtime.h>
#include <hip/hip_bf16.h>
#include <stdint.h>

typedef __attribute__((ext_vector_type(8))) __bf16 bf16x8;
typedef __attribute__((ext_vector_type(4))) float f32x4_t;
typedef __attribute__((ext_vector_type(2))) unsigned int u32x2;
typedef __attribute__((ext_vector_type(4))) unsigned int u32x4;
typedef unsigned int uint32;

#define EPSC 1e-6f

__device__ __forceinline__ unsigned short f2bf(float x){
  return __builtin_bit_cast(unsigned short, (__bf16)x);
}
__device__ __forceinline__ uint32 pk2(float a, float b){
  return (uint32)f2bf(a) | ((uint32)f2bf(b) << 16);
}

// ---------------- prep: WT[f][c] = bf16(W[c][f]) ----------------
__global__ void prep_wt(const float* __restrict__ W, unsigned short* __restrict__ WT){
  int c = blockIdx.x;
  int f = threadIdx.x;
  WT[(size_t)f*256 + c] = f2bf(W[(size_t)c*256 + f]);
}

// ---------------- hdeg: streaming H pass -> Hb bf16, row-sum partials, col-sum partials ----------------
__global__ __launch_bounds__(256, 4)
void hdeg_kernel(const float* __restrict__ H, float* __restrict__ dvpart,
                 float* __restrict__ departial, unsigned short* __restrict__ Hb){
  __shared__ float wavepart[64][4];
  const int t = threadIdx.x;
  const int lane = t & 63;
  const int w = t >> 6;
  const int rb = blockIdx.x & 255;
  const int cb = blockIdx.x >> 8;
  const size_t colbase = (size_t)cb*1024 + t*4;
  f32x4_t dacc = {0.f, 0.f, 0.f, 0.f};
  #pragma unroll 4
  for (int r = 0; r < 64; ++r){
    const int n = rb*64 + r;
    f32x4_t v = *(const f32x4_t*)(H + (size_t)n*4096 + colbase);
    dacc[0] += v[0]; dacc[1] += v[1]; dacc[2] += v[2]; dacc[3] += v[3];
    *(u32x2*)(Hb + (size_t)n*4096 + colbase) = u32x2{pk2(v[0], v[1]), pk2(v[2], v[3])};
    float rs = (v[0] + v[1]) + (v[2] + v[3]);
    #pragma unroll
    for (int d = 1; d < 64; d <<= 1) rs += __shfl_xor(rs, d);
    if (lane == 0) wavepart[r][w] = rs;
  }
  *(f32x4_t*)(departial + (size_t)rb*4096 + cb*1024 + t*4) = dacc;
  __syncthreads();
  if (t < 64){
    float s = wavepart[t][0] + wavepart[t][1] + wavepart[t][2] + wavepart[t][3];
    dvpart[(size_t)cb*16384 + rb*64 + t] = s;
  }
}

// ---------------- fin_dvs ----------------
__global__ void fin_dvs(const float* __restrict__ dvpart, float* __restrict__ dvs){
  int n = blockIdx.x*256 + threadIdx.x;
  float s = dvpart[n] + dvpart[16384 + n] + dvpart[2*16384 + n] + dvpart[3*16384 + n];
  dvs[n] = rsqrtf(s + EPSC);
}

// ---------------- reduce_de ----------------
__global__ void reduce_de(const float* __restrict__ departial, float* __restrict__ de){
  __shared__ float sm[4][64];
  int t = threadIdx.x;
  int c = blockIdx.x*64 + (t & 63);
  int part = t >> 6;
  float s = 0.f;
  #pragma unroll 4
  for (int rb = part*64; rb < part*64 + 64; ++rb)
    s += departial[(size_t)rb*4096 + c];
  sm[part][t & 63] = s;
  __syncthreads();
  if (t < 64) de[blockIdx.x*64 + t] = sm[0][t] + sm[1][t] + sm[2][t] + sm[3][t];
}

// ---------------- small MFMA GEMM (X = emb@W path), round-4 verified ----------------
template<int LDA, int KB, int NMT, int CHUNK>
__global__ __launch_bounds__(256, 2)
void gemm_x(const float* __restrict__ Af, const unsigned short* __restrict__ BT,
            const float* __restrict__ dvs, unsigned short* __restrict__ XsT)
{
  constexpr int NIT = CHUNK / 32;
  constexpr int ASZ = 64*32*2;
  constexpr int BSZ = 256*32*2;
  __shared__ __align__(16) char lds[2*ASZ + 2*BSZ];

  const int t = threadIdx.x;
  const int lane = t & 63;
  const int w = t >> 6;
  const int mt = blockIdx.x % NMT;
  const int s  = blockIdx.x / NMT;
  const int k0 = s * CHUNK;

  const int st_r  = t >> 2, st_cq = t & 3;

  f32x4_t acc[4][4] = {};
  f32x4_t pa[2];

  auto loadA = [&](int it){
    const float* p = Af + (size_t)(mt*64 + st_r)*LDA + k0 + it*32 + st_cq*4;
    pa[0] = *(const f32x4_t*)(p);
    pa[1] = *(const f32x4_t*)(p + 16);
  };

  auto gllB = [&](int it, int buf){
    char* bb = lds + 2*ASZ + buf*BSZ;
    const int kcur = k0 + it*32;
    const int swzh = ((lane & 3) ^ ((lane >> 2) & 3)) << 3;
    #pragma unroll
    for (int j = 0; j < 4; ++j){
      int chunk = w*4 + j;
      int frow = chunk*16 + (lane >> 2);
      const unsigned short* src = BT + (size_t)frow*KB + kcur + swzh;
      __builtin_amdgcn_global_load_lds((const __attribute__((address_space(1))) void*)src,
                                       (__attribute__((address_space(3))) void*)(bb + chunk*1024),
                                       16, 0, 0);
    }
  };

  auto stageA = [&](int buf){
    char* ab = lds + buf*ASZ;
    #pragma unroll
    for (int i = 0; i < 2; ++i){
      int f4 = st_cq + 4*i;
      uint32 lo = pk2(pa[i][0], pa[i][1]);
      uint32 hi = pk2(pa[i][2], pa[i][3]);
      *(u32x2*)(ab + st_r*64 + ((f4*8) ^ ((st_r & 3) << 4))) = u32x2{lo, hi};
    }
  };

  auto compute = [&](int buf){
    const char* ab = lds + buf*ASZ;
    const char* bb = lds + 2*ASZ + buf*BSZ;
    const int kswz = (((lane >> 4) ^ (lane & 3)) << 4);
    bf16x8 af[4], bfr[4];
    #pragma unroll
    for (int mi = 0; mi < 4; ++mi){
      int row = mi*16 + (lane & 15);
      af[mi] = *(const bf16x8*)(ab + row*64 + kswz);
    }
    #pragma unroll
    for (int fi = 0; fi < 4; ++fi){
      int row = w*64 + fi*16 + (lane & 15);
      bfr[fi] = *(const bf16x8*)(bb + row*64 + kswz);
    }
    #pragma unroll
    for (int mi = 0; mi < 4; ++mi){
      #pragma unroll
      for (int fi = 0; fi < 4; ++fi){
        acc[mi][fi] = __builtin_amdgcn_mfma_f32_16x16x32_bf16(af[mi], bfr[fi], acc[mi][fi], 0, 0, 0);
      }
    }
  };

  loadA(0);
  gllB(0, 0);
  stageA(0);
  __syncthreads();

  int cur = 0;
  #pragma unroll 1
  for (int it = 0; it < NIT; ++it){
    if (it + 1 < NIT){
      loadA(it + 1);
      gllB(it + 1, cur ^ 1);
    }
    compute(cur);
    if (it + 1 < NIT) stageA(cur ^ 1);
    __syncthreads();
    cur ^= 1;
  }

  #pragma unroll
  for (int mi = 0; mi < 4; ++mi){
    int n0 = mt*64 + mi*16 + ((lane >> 4) * 4);
    float d0 = dvs[n0], d1 = dvs[n0+1], d2 = dvs[n0+2], d3 = dvs[n0+3];
    #pragma unroll
    for (int fi = 0; fi < 4; ++fi){
      int f = w*64 + fi*16 + (lane & 15);
      uint32 lo = pk2(acc[mi][fi][0]*d0, acc[mi][fi][1]*d1);
      uint32 hi = pk2(acc[mi][fi][2]*d2, acc[mi][fi][3]*d3);
      *(u32x2*)(XsT + (size_t)f*16384 + n0) = u32x2{lo, hi};
    }
  }
}

// ---------------- big MFMA GEMM BM=128 x BN=256, BK=32, 512 thr, 3-buffer counted-vmcnt ----------------
// Staging/swizzle math identical to round-4 verified version; only the pipeline skeleton changed:
// 3 LDS buffers, loads issued 2 iters ahead, s_waitcnt vmcnt(N) + raw s_barrier (never drain-0 mid-loop).
// TRANS=0: A bf16 row-major via global_load_lds (3 vm loads/thread/iter -> vmcnt(3)).
// TRANS=1: A via reg-load + shuffle-transpose + ds_write (B: 2 vm loads/thread/iter -> vmcnt(2), lgkmcnt(0)).
template<int TRANS, int LDA, int KB, int NMT, int CHUNK>
__global__ __launch_bounds__(512, 1)
void gemm_h(const unsigned short* __restrict__ Ah, const unsigned short* __restrict__ BT,
            float* __restrict__ Cpart)
{
  constexpr int NIT = CHUNK / 32;
  constexpr int ASZ = 128*32*2;    // 8192 B
  constexpr int BSZ = 256*32*2;    // 16384 B
  __shared__ __align__(16) char lds[3*ASZ + 3*BSZ];   // 73728 B

  const int t = threadIdx.x;
  const int lane = t & 63;
  const int w = t >> 6;
  const int wm = w >> 2;
  const int wf = w & 3;
  const int mt = blockIdx.x % NMT;
  const int s  = blockIdx.x / NMT;
  const int k0 = s * CHUNK;

  f32x4_t acc[4][4] = {};
  u32x4 paw;

  auto gllB = [&](int it, int buf){
    char* bb = lds + 3*ASZ + buf*BSZ;
    const int kcur = k0 + it*32;
    const int swzh = ((lane & 3) ^ ((lane >> 2) & 3)) << 3;
    #pragma unroll
    for (int j = 0; j < 2; ++j){
      int chunk = w*2 + j;
      int frow = chunk*16 + (lane >> 2);
      const unsigned short* src = BT + (size_t)frow*KB + kcur + swzh;
      __builtin_amdgcn_global_load_lds((const __attribute__((address_space(1))) void*)src,
                                       (__attribute__((address_space(3))) void*)(bb + chunk*1024),
                                       16, 0, 0);
    }
  };

  auto gllA = [&](int it, int buf){   // TRANS=0
    char* ab = lds + buf*ASZ;
    const int kcur = k0 + it*32;
    const int arow = lane >> 2;
    const int kqs  = (lane & 3) ^ (arow & 3);
    const unsigned short* src = Ah + (size_t)(mt*128 + w*16 + arow)*LDA + kcur + kqs*8;
    __builtin_amdgcn_global_load_lds((const __attribute__((address_space(1))) void*)src,
                                     (__attribute__((address_space(3))) void*)(ab + w*1024),
                                     16, 0, 0);
  };

  auto loadA_tr = [&](int it){
    paw = *(const u32x4*)(Ah + (size_t)(k0 + it*32 + (t >> 4))*LDA + mt*128 + (t & 15)*8);
  };

  auto stageA_tr = [&](int buf){
    char* ab = lds + buf*ASZ;
    const int n = t >> 4;
    const int trq = t & 15;
    const bool odd = n & 1;
    const int np = n >> 1;
    uint32 pw[4];
    #pragma unroll
    for (int j = 0; j < 4; ++j) pw[j] = (uint32)__shfl_xor((int)paw[j], 16);
    #pragma unroll
    for (int j = 0; j < 4; ++j){
      int e = trq*8 + 2*j + (odd ? 1 : 0);
      uint32 word = odd ? ((pw[j] >> 16)      | (paw[j] & 0xFFFF0000u))
                        : ((paw[j] & 0xFFFFu) | (pw[j] << 16));
      int pq = (np >> 2) ^ (trq & 3);
      *(uint32*)(ab + e*64 + pq*16 + (np & 3)*4) = word;
    }
  };

  auto compute = [&](int buf){
    const char* ab = lds + buf*ASZ;
    const char* bb = lds + 3*ASZ + buf*BSZ;
    const int l15 = lane & 15;
    const int kq = lane >> 4;
    bf16x8 af[4], bfr[4];
    #pragma unroll
    for (int mi = 0; mi < 4; ++mi){
      int row = wm*64 + mi*16 + l15;
      int q = TRANS ? (kq ^ ((row >> 3) & 3)) : (kq ^ (row & 3));
      af[mi] = *(const bf16x8*)(ab + row*64 + q*16);
    }
    #pragma unroll
    for (int fi = 0; fi < 4; ++fi){
      int row = wf*64 + fi*16 + l15;
      bfr[fi] = *(const bf16x8*)(bb + row*64 + ((kq ^ (l15 & 3)) << 4));
    }
    #pragma unroll
    for (int mi = 0; mi < 4; ++mi){
      #pragma unroll
      for (int fi = 0; fi < 4; ++fi){
        acc[mi][fi] = __builtin_amdgcn_mfma_f32_16x16x32_bf16(af[mi], bfr[fi], acc[mi][fi], 0, 0, 0);
      }
    }
  };

  // prologue: fill buffers 0 and 1
  if (TRANS){
    loadA_tr(0);
    gllB(0, 0);
    gllB(1, 1);
    stageA_tr(0);                 // compiler waits paw's vmcnt; leaves B0,B1 in flight
    asm volatile("s_waitcnt vmcnt(2) lgkmcnt(0)" ::: "memory");   // B0 done, B1 in flight
  } else {
    gllB(0, 0); gllA(0, 0);
    gllB(1, 1); gllA(1, 1);
    asm volatile("s_waitcnt vmcnt(3) lgkmcnt(0)" ::: "memory");   // buf0's 3 done, buf1's 3 in flight
  }
  __builtin_amdgcn_s_barrier();

  #pragma unroll 1
  for (int it = 0; it < NIT; ++it){
    const int cur  = it % 3;
    const int nxt2 = (it + 2) % 3;
    if (TRANS){
      if (it + 1 < NIT) loadA_tr(it + 1);
      if (it + 2 < NIT) gllB(it + 2, nxt2);
      compute(cur);
      if (it + 1 < NIT){
        stageA_tr((it + 1) % 3);   // waits paw; ds_writes
        if (it + 2 < NIT) asm volatile("s_waitcnt vmcnt(2) lgkmcnt(0)" ::: "memory");
        else              asm volatile("s_waitcnt vmcnt(0) lgkmcnt(0)" ::: "memory");
        __builtin_amdgcn_s_barrier();
      }
    } else {
      if (it + 2 < NIT){ gllB(it + 2, nxt2); gllA(it + 2, nxt2); }
      compute(cur);
      if (it + 1 < NIT){
        if (it + 2 < NIT) asm volatile("s_waitcnt vmcnt(3) lgkmcnt(0)" ::: "memory");
        else              asm volatile("s_waitcnt vmcnt(0) lgkmcnt(0)" ::: "memory");
        __builtin_amdgcn_s_barrier();
      }
    }
  }

  float* C = Cpart + (size_t)s * (NMT*128) * 256;
  #pragma unroll
  for (int mi = 0; mi < 4; ++mi){
    int row0 = mt*128 + wm*64 + mi*16 + ((lane >> 4) * 4);
    #pragma unroll
    for (int fi = 0; fi < 4; ++fi){
      int f = wf*64 + fi*16 + (lane & 15);
      #pragma unroll
      for (int r = 0; r < 4; ++r)
        C[(size_t)(row0 + r)*256 + f] = acc[mi][fi][r];
    }
  }
}

// ---------------- mid: T1sT[f][e] = bf16( (sum_s T1part[s][e][f]) / (de[e]+eps) ) ----------------
__global__ void mid_kernel(const float* __restrict__ T1part, const float* __restrict__ de,
                           unsigned short* __restrict__ T1sT){
  int f = threadIdx.x;
  int e0 = blockIdx.x * 4;
  float v[4];
  #pragma unroll
  for (int r = 0; r < 4; ++r){
    float acc = 0.f;
    #pragma unroll
    for (int s = 0; s < 8; ++s)
      acc += T1part[(size_t)s*4096*256 + (size_t)(e0 + r)*256 + f];
    v[r] = acc / (de[e0 + r] + EPSC);
  }
  uint32 lo = pk2(v[0], v[1]);
  uint32 hi = pk2(v[2], v[3]);
  *(u32x2*)(T1sT + (size_t)f*4096 + e0) = u32x2{lo, hi};
}

// ---------------- fin: out[n][f] = relu(dvs[n] * (P0+P1)[n][f]), f32 ----------------
__global__ void fin_kernel(const float* __restrict__ P0, const float* __restrict__ P1,
                           const float* __restrict__ dvs, float* __restrict__ out){
  int gid = blockIdx.x*256 + threadIdx.x;
  int n = gid >> 5;
  int f0 = (gid & 31) * 8;
  size_t off = (size_t)n*256 + f0;
  f32x4_t a0 = *(const f32x4_t*)(P0 + off);
  f32x4_t a1 = *(const f32x4_t*)(P0 + off + 4);
  f32x4_t b0 = *(const f32x4_t*)(P1 + off);
  f32x4_t b1 = *(const f32x4_t*)(P1 + off + 4);
  float d = dvs[n];
  f32x4_t oa, ob;
  #pragma unroll
  for (int j = 0; j < 4; ++j){
    oa[j] = fmaxf((a0[j] + b0[j]) * d, 0.f);
    ob[j] = fmaxf((a1[j] + b1[j]) * d, 0.f);
  }
  *(f32x4_t*)(out + off) = oa;
  *(f32x4_t*)(out + off + 4) = ob;
}

extern "C" void kernel_launch(void* const* d_in, const int* in_sizes, int n_in,
                              void* d_out, int out_size, void* d_ws, size_t ws_size,
                              hipStream_t stream) {
  const float* emb = (const float*)d_in[0];   // [16384,256]
  const float* H   = (const float*)d_in[1];   // [16384,4096]
  const float* W   = (const float*)d_in[2];   // [256,256]
  float* out = (float*)d_out;                 // f32 [16384,256]

  char* ws = (char*)d_ws;
  float*          dvs       = (float*)(ws + 0);                  //   65536 B
  float*          de        = (float*)(ws + 65536);              //   16384 B
  unsigned short* WT        = (unsigned short*)(ws + 81920);     //  131072 B
  unsigned short* XsT       = (unsigned short*)(ws + 212992);    // 8388608 B  [256][16384] bf16
  unsigned short* T1sT      = (unsigned short*)(ws + 8601600);   // 2097152 B  [256][4096] bf16
  unsigned short* Hb        = (unsigned short*)(ws + 10698752);  // 134217728 B [16384][4096] bf16
  float*          T1part    = (float*)(ws + 144916480);          // 33554432 B [8][4096][256]
  float*          Opart     = (float*)(ws + 178470912);          // 33554432 B [2][16384][256]
  float*          departial = (float*)(ws + 212025344);          // 4194304 B [256][4096]
  float*          dvpart    = (float*)(ws + 216219648);          // 262144 B [4][16384]
  // total ws usage: 216,481,792 B

  prep_wt<<<256, 256, 0, stream>>>(W, WT);

  // single streaming pass over H: Hb + degree partials
  hdeg_kernel<<<1024, 256, 0, stream>>>(H, dvpart, departial, Hb);
  fin_dvs<<<64, 256, 0, stream>>>(dvpart, dvs);
  reduce_de<<<64, 256, 0, stream>>>(departial, de);

  // X: XsT[f][n] = bf16(dvs[n] * (emb@W)[n][f]);  M=16384, K=256
  gemm_x<256, 256, 256, 256><<<256, 256, 0, stream>>>(emb, WT, dvs, XsT);

  // GEMM1: T1part[s][e][f] = sum_{n in chunk s} Hb[n][e]*Xs[n][f];  M=4096 (e), K=16384 (n), split-K=8
  gemm_h<1, 4096, 16384, 32, 2048><<<256, 512, 0, stream>>>(Hb, XsT, T1part);

  // T1s = De^-1 * sum(T1part), bf16 transposed
  mid_kernel<<<1024, 256, 0, stream>>>(T1part, de, T1sT);

  // GEMM2: Opart[s][n][f] = sum_{e in chunk s} Hb[n][e]*T1s[e][f];  M=16384 (n), K=4096 (e), split-K=2
  gemm_h<0, 4096, 4096, 128, 2048><<<256, 512, 0, stream>>>(Hb, T1sT, Opart);

  // out = relu(dvs[n] * (Opart0 + Opart1))
  fin_kernel<<<2048, 256, 0, stream>>>(Opart, Opart + (size_t)16384*256, dvs, out);
}

// Round 9
// 213.783 us; speedup vs baseline: 1.3507x; 1.1303x over previous
//
#include <hip/hip_runtime.h>
#include <hip/hip_bf16.h>
#include <stdint.h>

typedef __attribute__((ext_vector_type(8))) __bf16 bf16x8;
typedef __attribute__((ext_vector_type(4))) float f32x4_t;
typedef __attribute__((ext_vector_type(2))) unsigned int u32x2;
typedef __attribute__((ext_vector_type(4))) unsigned int u32x4;
typedef unsigned int uint32;

#define EPSC 1e-6f

__device__ __forceinline__ unsigned short f2bf(float x){
  return __builtin_bit_cast(unsigned short, (__bf16)x);
}
__device__ __forceinline__ uint32 pk2(float a, float b){
  return (uint32)f2bf(a) | ((uint32)f2bf(b) << 16);
}
__device__ __forceinline__ float bfu2f(unsigned short u){
  return __builtin_bit_cast(float, ((uint32)u) << 16);
}

// ---------------- prep: WT[f][c] = bf16(W[c][f]) ----------------
__global__ void prep_wt(const float* __restrict__ W, unsigned short* __restrict__ WT){
  int c = blockIdx.x;
  int f = threadIdx.x;
  WT[(size_t)f*256 + c] = f2bf(W[(size_t)c*256 + f]);
}

// ---------------- hdeg: streaming H pass -> Hb bf16, row-sum partials, col-sum partials ----------------
__global__ __launch_bounds__(256, 4)
void hdeg_kernel(const float* __restrict__ H, float* __restrict__ dvpart,
                 float* __restrict__ departial, unsigned short* __restrict__ Hb){
  __shared__ float wavepart[64][4];
  const int t = threadIdx.x;
  const int lane = t & 63;
  const int w = t >> 6;
  const int rb = blockIdx.x & 255;
  const int cb = blockIdx.x >> 8;
  const size_t colbase = (size_t)cb*1024 + t*4;
  f32x4_t dacc = {0.f, 0.f, 0.f, 0.f};
  #pragma unroll 4
  for (int r = 0; r < 64; ++r){
    const int n = rb*64 + r;
    f32x4_t v = *(const f32x4_t*)(H + (size_t)n*4096 + colbase);
    dacc[0] += v[0]; dacc[1] += v[1]; dacc[2] += v[2]; dacc[3] += v[3];
    *(u32x2*)(Hb + (size_t)n*4096 + colbase) = u32x2{pk2(v[0], v[1]), pk2(v[2], v[3])};
    float rs = (v[0] + v[1]) + (v[2] + v[3]);
    #pragma unroll
    for (int d = 1; d < 64; d <<= 1) rs += __shfl_xor(rs, d);
    if (lane == 0) wavepart[r][w] = rs;
  }
  *(f32x4_t*)(departial + (size_t)rb*4096 + cb*1024 + t*4) = dacc;
  __syncthreads();
  if (t < 64){
    float s = wavepart[t][0] + wavepart[t][1] + wavepart[t][2] + wavepart[t][3];
    dvpart[(size_t)cb*16384 + rb*64 + t] = s;
  }
}

// ---------------- fin_dvs ----------------
__global__ void fin_dvs(const float* __restrict__ dvpart, float* __restrict__ dvs){
  int n = blockIdx.x*256 + threadIdx.x;
  float s = dvpart[n] + dvpart[16384 + n] + dvpart[2*16384 + n] + dvpart[3*16384 + n];
  dvs[n] = rsqrtf(s + EPSC);
}

// ---------------- reduce_de ----------------
__global__ void reduce_de(const float* __restrict__ departial, float* __restrict__ de){
  __shared__ float sm[4][64];
  int t = threadIdx.x;
  int c = blockIdx.x*64 + (t & 63);
  int part = t >> 6;
  float s = 0.f;
  #pragma unroll 4
  for (int rb = part*64; rb < part*64 + 64; ++rb)
    s += departial[(size_t)rb*4096 + c];
  sm[part][t & 63] = s;
  __syncthreads();
  if (t < 64) de[blockIdx.x*64 + t] = sm[0][t] + sm[1][t] + sm[2][t] + sm[3][t];
}

// ---------------- small MFMA GEMM (X = emb@W path), round-4 verified ----------------
template<int LDA, int KB, int NMT, int CHUNK>
__global__ __launch_bounds__(256, 2)
void gemm_x(const float* __restrict__ Af, const unsigned short* __restrict__ BT,
            const float* __restrict__ dvs, unsigned short* __restrict__ XsT)
{
  constexpr int NIT = CHUNK / 32;
  constexpr int ASZ = 64*32*2;
  constexpr int BSZ = 256*32*2;
  __shared__ __align__(16) char lds[2*ASZ + 2*BSZ];

  const int t = threadIdx.x;
  const int lane = t & 63;
  const int w = t >> 6;
  const int mt = blockIdx.x % NMT;
  const int s  = blockIdx.x / NMT;
  const int k0 = s * CHUNK;

  const int st_r  = t >> 2, st_cq = t & 3;

  f32x4_t acc[4][4] = {};
  f32x4_t pa[2];

  auto loadA = [&](int it){
    const float* p = Af + (size_t)(mt*64 + st_r)*LDA + k0 + it*32 + st_cq*4;
    pa[0] = *(const f32x4_t*)(p);
    pa[1] = *(const f32x4_t*)(p + 16);
  };

  auto gllB = [&](int it, int buf){
    char* bb = lds + 2*ASZ + buf*BSZ;
    const int kcur = k0 + it*32;
    const int swzh = ((lane & 3) ^ ((lane >> 2) & 3)) << 3;
    #pragma unroll
    for (int j = 0; j < 4; ++j){
      int chunk = w*4 + j;
      int frow = chunk*16 + (lane >> 2);
      const unsigned short* src = BT + (size_t)frow*KB + kcur + swzh;
      __builtin_amdgcn_global_load_lds((const __attribute__((address_space(1))) void*)src,
                                       (__attribute__((address_space(3))) void*)(bb + chunk*1024),
                                       16, 0, 0);
    }
  };

  auto stageA = [&](int buf){
    char* ab = lds + buf*ASZ;
    #pragma unroll
    for (int i = 0; i < 2; ++i){
      int f4 = st_cq + 4*i;
      uint32 lo = pk2(pa[i][0], pa[i][1]);
      uint32 hi = pk2(pa[i][2], pa[i][3]);
      *(u32x2*)(ab + st_r*64 + ((f4*8) ^ ((st_r & 3) << 4))) = u32x2{lo, hi};
    }
  };

  auto compute = [&](int buf){
    const char* ab = lds + buf*ASZ;
    const char* bb = lds + 2*ASZ + buf*BSZ;
    const int kswz = (((lane >> 4) ^ (lane & 3)) << 4);
    bf16x8 af[4], bfr[4];
    #pragma unroll
    for (int mi = 0; mi < 4; ++mi){
      int row = mi*16 + (lane & 15);
      af[mi] = *(const bf16x8*)(ab + row*64 + kswz);
    }
    #pragma unroll
    for (int fi = 0; fi < 4; ++fi){
      int row = w*64 + fi*16 + (lane & 15);
      bfr[fi] = *(const bf16x8*)(bb + row*64 + kswz);
    }
    #pragma unroll
    for (int mi = 0; mi < 4; ++mi){
      #pragma unroll
      for (int fi = 0; fi < 4; ++fi){
        acc[mi][fi] = __builtin_amdgcn_mfma_f32_16x16x32_bf16(af[mi], bfr[fi], acc[mi][fi], 0, 0, 0);
      }
    }
  };

  loadA(0);
  gllB(0, 0);
  stageA(0);
  __syncthreads();

  int cur = 0;
  #pragma unroll 1
  for (int it = 0; it < NIT; ++it){
    if (it + 1 < NIT){
      loadA(it + 1);
      gllB(it + 1, cur ^ 1);
    }
    compute(cur);
    if (it + 1 < NIT) stageA(cur ^ 1);
    __syncthreads();
    cur ^= 1;
  }

  #pragma unroll
  for (int mi = 0; mi < 4; ++mi){
    int n0 = mt*64 + mi*16 + ((lane >> 4) * 4);
    float d0 = dvs[n0], d1 = dvs[n0+1], d2 = dvs[n0+2], d3 = dvs[n0+3];
    #pragma unroll
    for (int fi = 0; fi < 4; ++fi){
      int f = w*64 + fi*16 + (lane & 15);
      uint32 lo = pk2(acc[mi][fi][0]*d0, acc[mi][fi][1]*d1);
      uint32 hi = pk2(acc[mi][fi][2]*d2, acc[mi][fi][3]*d3);
      *(u32x2*)(XsT + (size_t)f*16384 + n0) = u32x2{lo, hi};
    }
  }
}

// ---------------- big MFMA GEMM BM=128 x BN=256, BK=32, 512 thr ----------------
// Depth-5 LDS pipeline, issue-4-ahead, counted vmcnt (steady 9, tail 6/3/0), bf16 partial output.
// Per tile: 3 vm ops/thread (TRANS=0: 2 gllB + 1 gllA; TRANS=1: 1 A-reg load + 2 gllB).
// TRANS=1: 4-deep A-register pipeline via 4-unrolled main loop with static slot naming.
// Staging/swizzle math identical to round-4-verified kernels.
template<int TRANS, int LDA, int KB, int NMT, int CHUNK>
__global__ __launch_bounds__(512, 1)
void gemm_h(const unsigned short* __restrict__ Ah, const unsigned short* __restrict__ BT,
            unsigned short* __restrict__ Cp)
{
  constexpr int NIT = CHUNK / 32;
  static_assert(NIT % 4 == 0 && NIT >= 8, "tail/unroll assumptions");
  constexpr int ASZ = 128*32*2;    // 8192 B
  constexpr int BSZ = 256*32*2;    // 16384 B
  __shared__ __align__(16) char lds[5*ASZ + 5*BSZ];   // 122880 B

  const int t = threadIdx.x;
  const int lane = t & 63;
  const int w = t >> 6;
  const int wm = w >> 2;
  const int wf = w & 3;
  const int mt = blockIdx.x % NMT;
  const int s  = blockIdx.x / NMT;
  const int k0 = s * CHUNK;

  f32x4_t acc[4][4] = {};

  auto gllB = [&](int it, int buf){
    char* bb = lds + 5*ASZ + buf*BSZ;
    const int kcur = k0 + it*32;
    const int swzh = ((lane & 3) ^ ((lane >> 2) & 3)) << 3;
    #pragma unroll
    for (int j = 0; j < 2; ++j){
      int chunk = w*2 + j;
      int frow = chunk*16 + (lane >> 2);
      const unsigned short* src = BT + (size_t)frow*KB + kcur + swzh;
      __builtin_amdgcn_global_load_lds((const __attribute__((address_space(1))) void*)src,
                                       (__attribute__((address_space(3))) void*)(bb + chunk*1024),
                                       16, 0, 0);
    }
  };

  auto gllA = [&](int it, int buf){   // TRANS=0
    char* ab = lds + buf*ASZ;
    const int kcur = k0 + it*32;
    const int arow = lane >> 2;
    const int kqs  = (lane & 3) ^ (arow & 3);
    const unsigned short* src = Ah + (size_t)(mt*128 + w*16 + arow)*LDA + kcur + kqs*8;
    __builtin_amdgcn_global_load_lds((const __attribute__((address_space(1))) void*)src,
                                     (__attribute__((address_space(3))) void*)(ab + w*1024),
                                     16, 0, 0);
  };

  auto loadA_tr = [&](int it) -> u32x4 {
    return *(const u32x4*)(Ah + (size_t)(k0 + it*32 + (t >> 4))*LDA + mt*128 + (t & 15)*8);
  };

  auto stageA_tr = [&](int buf, u32x4 paw){
    char* ab = lds + buf*ASZ;
    const int n = t >> 4;
    const int trq = t & 15;
    const bool odd = n & 1;
    const int np = n >> 1;
    uint32 pw[4];
    #pragma unroll
    for (int j = 0; j < 4; ++j) pw[j] = (uint32)__shfl_xor((int)paw[j], 16);
    #pragma unroll
    for (int j = 0; j < 4; ++j){
      int e = trq*8 + 2*j + (odd ? 1 : 0);
      uint32 word = odd ? ((pw[j] >> 16)      | (paw[j] & 0xFFFF0000u))
                        : ((paw[j] & 0xFFFFu) | (pw[j] << 16));
      int pq = (np >> 2) ^ (trq & 3);
      *(uint32*)(ab + e*64 + pq*16 + (np & 3)*4) = word;
    }
  };

  auto compute = [&](int buf){
    const char* ab = lds + buf*ASZ;
    const char* bb = lds + 5*ASZ + buf*BSZ;
    const int l15 = lane & 15;
    const int kq = lane >> 4;
    bf16x8 af[4], bfr[4];
    #pragma unroll
    for (int mi = 0; mi < 4; ++mi){
      int row = wm*64 + mi*16 + l15;
      int q = TRANS ? (kq ^ ((row >> 3) & 3)) : (kq ^ (row & 3));
      af[mi] = *(const bf16x8*)(ab + row*64 + q*16);
    }
    #pragma unroll
    for (int fi = 0; fi < 4; ++fi){
      int row = wf*64 + fi*16 + l15;
      bfr[fi] = *(const bf16x8*)(bb + row*64 + ((kq ^ (l15 & 3)) << 4));
    }
    #pragma unroll
    for (int mi = 0; mi < 4; ++mi){
      #pragma unroll
      for (int fi = 0; fi < 4; ++fi){
        acc[mi][fi] = __builtin_amdgcn_mfma_f32_16x16x32_bf16(af[mi], bfr[fi], acc[mi][fi], 0, 0, 0);
      }
    }
  };

  auto nxt5 = [](int b){ return b + 1 >= 5 ? 0 : b + 1; };
  auto pls4 = [](int b){ return b + 4 >= 5 ? b - 1 : b + 4; };

  if (TRANS){
    // A-reg slots: p0..p3 hold A(m) with m%4 == slot index.
    u32x4 p0, p1, p2, p3;
    p0 = loadA_tr(0); gllB(0, 0);
    p1 = loadA_tr(1); gllB(1, 1);
    p2 = loadA_tr(2); gllB(2, 2);
    p3 = loadA_tr(3); gllB(3, 3);
    stageA_tr(0, p0);                       // implicit wait retires only p0
    asm volatile("s_waitcnt vmcnt(9) lgkmcnt(0)" ::: "memory");  // B(0) done
    __builtin_amdgcn_s_barrier();

    int cur = 0;
    #pragma unroll 1
    for (int jt = 0; jt < NIT - 4; jt += 4){
      // it = jt+0: load slot0, stage slot1
      p0 = loadA_tr(jt + 4);
      gllB(jt + 4, pls4(cur));
      compute(cur);
      { int sb = nxt5(cur); stageA_tr(sb, p1); cur = sb; }
      asm volatile("s_waitcnt vmcnt(9) lgkmcnt(0)" ::: "memory");
      __builtin_amdgcn_s_barrier();
      // it = jt+1: load slot1, stage slot2
      p1 = loadA_tr(jt + 5);
      gllB(jt + 5, pls4(cur));
      compute(cur);
      { int sb = nxt5(cur); stageA_tr(sb, p2); cur = sb; }
      asm volatile("s_waitcnt vmcnt(9) lgkmcnt(0)" ::: "memory");
      __builtin_amdgcn_s_barrier();
      // it = jt+2: load slot2, stage slot3
      p2 = loadA_tr(jt + 6);
      gllB(jt + 6, pls4(cur));
      compute(cur);
      { int sb = nxt5(cur); stageA_tr(sb, p3); cur = sb; }
      asm volatile("s_waitcnt vmcnt(9) lgkmcnt(0)" ::: "memory");
      __builtin_amdgcn_s_barrier();
      // it = jt+3: load slot3, stage slot0
      p3 = loadA_tr(jt + 7);
      gllB(jt + 7, pls4(cur));
      compute(cur);
      { int sb = nxt5(cur); stageA_tr(sb, p0); cur = sb; }
      asm volatile("s_waitcnt vmcnt(9) lgkmcnt(0)" ::: "memory");
      __builtin_amdgcn_s_barrier();
    }
    // tail: it = NIT-4 .. NIT-1 (stages use p1, p2, p3)
    compute(cur);
    { int sb = nxt5(cur); stageA_tr(sb, p1); cur = sb; }
    asm volatile("s_waitcnt vmcnt(6) lgkmcnt(0)" ::: "memory");
    __builtin_amdgcn_s_barrier();
    compute(cur);
    { int sb = nxt5(cur); stageA_tr(sb, p2); cur = sb; }
    asm volatile("s_waitcnt vmcnt(3) lgkmcnt(0)" ::: "memory");
    __builtin_amdgcn_s_barrier();
    compute(cur);
    { int sb = nxt5(cur); stageA_tr(sb, p3); cur = sb; }
    asm volatile("s_waitcnt vmcnt(0) lgkmcnt(0)" ::: "memory");
    __builtin_amdgcn_s_barrier();
    compute(cur);
  } else {
    gllB(0, 0); gllA(0, 0);
    gllB(1, 1); gllA(1, 1);
    gllB(2, 2); gllA(2, 2);
    gllB(3, 3); gllA(3, 3);
    asm volatile("s_waitcnt vmcnt(9)" ::: "memory");   // tile 0's 3 done
    __builtin_amdgcn_s_barrier();

    int cur = 0;
    #pragma unroll 1
    for (int it = 0; it < NIT - 4; ++it){
      int nb = pls4(cur);
      gllB(it + 4, nb); gllA(it + 4, nb);
      compute(cur);
      asm volatile("s_waitcnt vmcnt(9)" ::: "memory");
      __builtin_amdgcn_s_barrier();
      cur = nxt5(cur);
    }
    compute(cur);
    asm volatile("s_waitcnt vmcnt(6)" ::: "memory");
    __builtin_amdgcn_s_barrier();
    cur = nxt5(cur);
    compute(cur);
    asm volatile("s_waitcnt vmcnt(3)" ::: "memory");
    __builtin_amdgcn_s_barrier();
    cur = nxt5(cur);
    compute(cur);
    asm volatile("s_waitcnt vmcnt(0)" ::: "memory");
    __builtin_amdgcn_s_barrier();
    cur = nxt5(cur);
    compute(cur);
  }

  // epilogue: bf16 split-K partial
  unsigned short* C = Cp + (size_t)s * (NMT*128) * 256;
  #pragma unroll
  for (int mi = 0; mi < 4; ++mi){
    int row0 = mt*128 + wm*64 + mi*16 + ((lane >> 4) * 4);
    #pragma unroll
    for (int fi = 0; fi < 4; ++fi){
      int f = wf*64 + fi*16 + (lane & 15);
      #pragma unroll
      for (int r = 0; r < 4; ++r)
        C[(size_t)(row0 + r)*256 + f] = f2bf(acc[mi][fi][r]);
    }
  }
}

// ---------------- mid: T1sT[f][e] = bf16( (sum_s bf2f(T1p[s][e][f])) / (de[e]+eps) ) ----------------
__global__ void mid_kernel(const unsigned short* __restrict__ T1p, const float* __restrict__ de,
                           unsigned short* __restrict__ T1sT){
  int f = threadIdx.x;
  int e0 = blockIdx.x * 4;
  float v[4];
  #pragma unroll
  for (int r = 0; r < 4; ++r){
    float acc = 0.f;
    #pragma unroll
    for (int s = 0; s < 8; ++s)
      acc += bfu2f(T1p[(size_t)s*4096*256 + (size_t)(e0 + r)*256 + f]);
    v[r] = acc / (de[e0 + r] + EPSC);
  }
  uint32 lo = pk2(v[0], v[1]);
  uint32 hi = pk2(v[2], v[3]);
  *(u32x2*)(T1sT + (size_t)f*4096 + e0) = u32x2{lo, hi};
}

// ---------------- fin: out[n][f] = relu(dvs[n] * (P0+P1)[n][f]), bf16 partials -> f32 ----------------
__global__ void fin_kernel(const unsigned short* __restrict__ P0, const unsigned short* __restrict__ P1,
                           const float* __restrict__ dvs, float* __restrict__ out){
  int gid = blockIdx.x*256 + threadIdx.x;
  int n = gid >> 5;
  int f0 = (gid & 31) * 8;
  size_t off = (size_t)n*256 + f0;
  u32x4 a = *(const u32x4*)(P0 + off);
  u32x4 b = *(const u32x4*)(P1 + off);
  float d = dvs[n];
  f32x4_t o1, o2;
  #pragma unroll
  for (int j = 0; j < 4; ++j){
    float alo = __builtin_bit_cast(float, a[j] << 16);
    float ahi = __builtin_bit_cast(float, a[j] & 0xFFFF0000u);
    float blo = __builtin_bit_cast(float, b[j] << 16);
    float bhi = __builtin_bit_cast(float, b[j] & 0xFFFF0000u);
    float lo = fmaxf((alo + blo) * d, 0.f);
    float hi = fmaxf((ahi + bhi) * d, 0.f);
    if (j < 2){ o1[2*j] = lo; o1[2*j + 1] = hi; }
    else      { o2[2*(j-2)] = lo; o2[2*(j-2) + 1] = hi; }
  }
  *(f32x4_t*)(out + off) = o1;
  *(f32x4_t*)(out + off + 4) = o2;
}

extern "C" void kernel_launch(void* const* d_in, const int* in_sizes, int n_in,
                              void* d_out, int out_size, void* d_ws, size_t ws_size,
                              hipStream_t stream) {
  const float* emb = (const float*)d_in[0];   // [16384,256]
  const float* H   = (const float*)d_in[1];   // [16384,4096]
  const float* W   = (const float*)d_in[2];   // [256,256]
  float* out = (float*)d_out;                 // f32 [16384,256]

  char* ws = (char*)d_ws;
  float*          dvs       = (float*)(ws + 0);                  //   65536 B
  float*          de        = (float*)(ws + 65536);              //   16384 B
  unsigned short* WT        = (unsigned short*)(ws + 81920);     //  131072 B
  unsigned short* XsT       = (unsigned short*)(ws + 212992);    // 8388608 B  [256][16384] bf16
  unsigned short* T1sT      = (unsigned short*)(ws + 8601600);   // 2097152 B  [256][4096] bf16
  unsigned short* Hb        = (unsigned short*)(ws + 10698752);  // 134217728 B [16384][4096] bf16
  unsigned short* T1p16     = (unsigned short*)(ws + 144916480); // 16777216 B [8][4096][256] bf16
  unsigned short* Op16      = (unsigned short*)(ws + 161693696); // 16777216 B [2][16384][256] bf16
  float*          departial = (float*)(ws + 178470912);          // 4194304 B [256][4096]
  float*          dvpart    = (float*)(ws + 182665216);          // 262144 B [4][16384]
  // total ws usage: 182,927,360 B

  prep_wt<<<256, 256, 0, stream>>>(W, WT);

  // single streaming pass over H: Hb + degree partials
  hdeg_kernel<<<1024, 256, 0, stream>>>(H, dvpart, departial, Hb);
  fin_dvs<<<64, 256, 0, stream>>>(dvpart, dvs);
  reduce_de<<<64, 256, 0, stream>>>(departial, de);

  // X: XsT[f][n] = bf16(dvs[n] * (emb@W)[n][f]);  M=16384, K=256
  gemm_x<256, 256, 256, 256><<<256, 256, 0, stream>>>(emb, WT, dvs, XsT);

  // GEMM1: T1p16[s][e][f] = bf16(sum_{n in chunk s} Hb[n][e]*Xs[n][f]);  M=4096 (e), K=16384 (n), split-K=8
  gemm_h<1, 4096, 16384, 32, 2048><<<256, 512, 0, stream>>>(Hb, XsT, T1p16);

  // T1s = De^-1 * sum(T1p16), bf16 transposed
  mid_kernel<<<1024, 256, 0, stream>>>(T1p16, de, T1sT);

  // GEMM2: Op16[s][n][f] = bf16(sum_{e in chunk s} Hb[n][e]*T1s[e][f]);  M=16384 (n), K=4096 (e), split-K=2
  gemm_h<0, 4096, 4096, 128, 2048><<<256, 512, 0, stream>>>(Hb, T1sT, Op16);

  // out = relu(dvs[n] * (Op16_0 + Op16_1))
  fin_kernel<<<2048, 256, 0, stream>>>(Op16, Op16 + (size_t)16384*256, dvs, out);
}

// Round 10
// 212.679 us; speedup vs baseline: 1.3577x; 1.0052x over previous
//
#include <hip/hip_runtime.h>
#include <hip/hip_bf16.h>
#include <stdint.h>

typedef __attribute__((ext_vector_type(8))) __bf16 bf16x8;
typedef __attribute__((ext_vector_type(4))) float f32x4_t;
typedef __attribute__((ext_vector_type(2))) unsigned int u32x2;
typedef __attribute__((ext_vector_type(4))) unsigned int u32x4;
typedef unsigned int uint32;

#define EPSC 1e-6f

__device__ __forceinline__ unsigned short f2bf(float x){
  return __builtin_bit_cast(unsigned short, (__bf16)x);
}
__device__ __forceinline__ uint32 pk2(float a, float b){
  return (uint32)f2bf(a) | ((uint32)f2bf(b) << 16);
}
__device__ __forceinline__ float bfu2f(unsigned short u){
  return __builtin_bit_cast(float, ((uint32)u) << 16);
}

// ---------------- prep: WT[f][c] = bf16(W[c][f]) ----------------
__global__ void prep_wt(const float* __restrict__ W, unsigned short* __restrict__ WT){
  int c = blockIdx.x;
  int f = threadIdx.x;
  WT[(size_t)f*256 + c] = f2bf(W[(size_t)c*256 + f]);
}

// ---------------- hdeg: streaming H pass -> Hb bf16, row-sum partials, col-sum partials ----------------
__global__ __launch_bounds__(256, 4)
void hdeg_kernel(const float* __restrict__ H, float* __restrict__ dvpart,
                 float* __restrict__ departial, unsigned short* __restrict__ Hb){
  __shared__ float wavepart[64][4];
  const int t = threadIdx.x;
  const int lane = t & 63;
  const int w = t >> 6;
  const int rb = blockIdx.x & 255;
  const int cb = blockIdx.x >> 8;
  const size_t colbase = (size_t)cb*1024 + t*4;
  f32x4_t dacc = {0.f, 0.f, 0.f, 0.f};
  #pragma unroll 4
  for (int r = 0; r < 64; ++r){
    const int n = rb*64 + r;
    f32x4_t v = *(const f32x4_t*)(H + (size_t)n*4096 + colbase);
    dacc[0] += v[0]; dacc[1] += v[1]; dacc[2] += v[2]; dacc[3] += v[3];
    *(u32x2*)(Hb + (size_t)n*4096 + colbase) = u32x2{pk2(v[0], v[1]), pk2(v[2], v[3])};
    float rs = (v[0] + v[1]) + (v[2] + v[3]);
    #pragma unroll
    for (int d = 1; d < 64; d <<= 1) rs += __shfl_xor(rs, d);
    if (lane == 0) wavepart[r][w] = rs;
  }
  *(f32x4_t*)(departial + (size_t)rb*4096 + cb*1024 + t*4) = dacc;
  __syncthreads();
  if (t < 64){
    float s = wavepart[t][0] + wavepart[t][1] + wavepart[t][2] + wavepart[t][3];
    dvpart[(size_t)cb*16384 + rb*64 + t] = s;
  }
}

// ---------------- finish_deg: blocks 0..63 -> dvs, 64..127 -> de ----------------
__global__ void finish_deg(const float* __restrict__ dvpart, const float* __restrict__ departial,
                           float* __restrict__ dvs, float* __restrict__ de){
  __shared__ float sm[4][64];
  int t = threadIdx.x;
  if (blockIdx.x < 64){
    int n = blockIdx.x*256 + t;
    float s = dvpart[n] + dvpart[16384 + n] + dvpart[2*16384 + n] + dvpart[3*16384 + n];
    dvs[n] = rsqrtf(s + EPSC);
  } else {
    int b = blockIdx.x - 64;
    int c = b*64 + (t & 63);
    int part = t >> 6;
    float s = 0.f;
    #pragma unroll 4
    for (int rb = part*64; rb < part*64 + 64; ++rb)
      s += departial[(size_t)rb*4096 + c];
    sm[part][t & 63] = s;
    __syncthreads();
    if (t < 64) de[b*64 + t] = sm[0][t] + sm[1][t] + sm[2][t] + sm[3][t];
  }
}

// ---------------- small MFMA GEMM (X = emb@W path), round-4 verified ----------------
template<int LDA, int KB, int NMT, int CHUNK>
__global__ __launch_bounds__(256, 2)
void gemm_x(const float* __restrict__ Af, const unsigned short* __restrict__ BT,
            const float* __restrict__ dvs, unsigned short* __restrict__ XsT)
{
  constexpr int NIT = CHUNK / 32;
  constexpr int ASZ = 64*32*2;
  constexpr int BSZ = 256*32*2;
  __shared__ __align__(16) char lds[2*ASZ + 2*BSZ];

  const int t = threadIdx.x;
  const int lane = t & 63;
  const int w = t >> 6;
  const int mt = blockIdx.x % NMT;
  const int s  = blockIdx.x / NMT;
  const int k0 = s * CHUNK;

  const int st_r  = t >> 2, st_cq = t & 3;

  f32x4_t acc[4][4] = {};
  f32x4_t pa[2];

  auto loadA = [&](int it){
    const float* p = Af + (size_t)(mt*64 + st_r)*LDA + k0 + it*32 + st_cq*4;
    pa[0] = *(const f32x4_t*)(p);
    pa[1] = *(const f32x4_t*)(p + 16);
  };

  auto gllB = [&](int it, int buf){
    char* bb = lds + 2*ASZ + buf*BSZ;
    const int kcur = k0 + it*32;
    const int swzh = ((lane & 3) ^ ((lane >> 2) & 3)) << 3;
    #pragma unroll
    for (int j = 0; j < 4; ++j){
      int chunk = w*4 + j;
      int frow = chunk*16 + (lane >> 2);
      const unsigned short* src = BT + (size_t)frow*KB + kcur + swzh;
      __builtin_amdgcn_global_load_lds((const __attribute__((address_space(1))) void*)src,
                                       (__attribute__((address_space(3))) void*)(bb + chunk*1024),
                                       16, 0, 0);
    }
  };

  auto stageA = [&](int buf){
    char* ab = lds + buf*ASZ;
    #pragma unroll
    for (int i = 0; i < 2; ++i){
      int f4 = st_cq + 4*i;
      uint32 lo = pk2(pa[i][0], pa[i][1]);
      uint32 hi = pk2(pa[i][2], pa[i][3]);
      *(u32x2*)(ab + st_r*64 + ((f4*8) ^ ((st_r & 3) << 4))) = u32x2{lo, hi};
    }
  };

  auto compute = [&](int buf){
    const char* ab = lds + buf*ASZ;
    const char* bb = lds + 2*ASZ + buf*BSZ;
    const int kswz = (((lane >> 4) ^ (lane & 3)) << 4);
    bf16x8 af[4], bfr[4];
    #pragma unroll
    for (int mi = 0; mi < 4; ++mi){
      int row = mi*16 + (lane & 15);
      af[mi] = *(const bf16x8*)(ab + row*64 + kswz);
    }
    #pragma unroll
    for (int fi = 0; fi < 4; ++fi){
      int row = w*64 + fi*16 + (lane & 15);
      bfr[fi] = *(const bf16x8*)(bb + row*64 + kswz);
    }
    #pragma unroll
    for (int mi = 0; mi < 4; ++mi){
      #pragma unroll
      for (int fi = 0; fi < 4; ++fi){
        acc[mi][fi] = __builtin_amdgcn_mfma_f32_16x16x32_bf16(af[mi], bfr[fi], acc[mi][fi], 0, 0, 0);
      }
    }
  };

  loadA(0);
  gllB(0, 0);
  stageA(0);
  __syncthreads();

  int cur = 0;
  #pragma unroll 1
  for (int it = 0; it < NIT; ++it){
    if (it + 1 < NIT){
      loadA(it + 1);
      gllB(it + 1, cur ^ 1);
    }
    compute(cur);
    if (it + 1 < NIT) stageA(cur ^ 1);
    __syncthreads();
    cur ^= 1;
  }

  #pragma unroll
  for (int mi = 0; mi < 4; ++mi){
    int n0 = mt*64 + mi*16 + ((lane >> 4) * 4);
    float d0 = dvs[n0], d1 = dvs[n0+1], d2 = dvs[n0+2], d3 = dvs[n0+3];
    #pragma unroll
    for (int fi = 0; fi < 4; ++fi){
      int f = w*64 + fi*16 + (lane & 15);
      uint32 lo = pk2(acc[mi][fi][0]*d0, acc[mi][fi][1]*d1);
      uint32 hi = pk2(acc[mi][fi][2]*d2, acc[mi][fi][3]*d3);
      *(u32x2*)(XsT + (size_t)f*16384 + n0) = u32x2{lo, hi};
    }
  }
}

// ---------------- big MFMA GEMM BM=128 x BN=256, 512 thr ----------------
// BK=64 phases (2 x 32-k slices per barrier), 3-tile LDS pipeline, issue-2-tiles-ahead,
// counted vmcnt (steady 6, tail 0), bf16 partial output.
// All slice-level staging/swizzle/compute math bit-identical to round-9-verified kernels.
template<int TRANS, int LDA, int KB, int NMT, int CHUNK>
__global__ __launch_bounds__(512, 1)
void gemm_h(const unsigned short* __restrict__ Ah, const unsigned short* __restrict__ BT,
            unsigned short* __restrict__ Cp)
{
  constexpr int NIT = CHUNK / 32;   // 64 slices
  constexpr int NT  = NIT / 2;      // 32 tiles (BK=64)
  static_assert(NT % 2 == 0 && NT >= 4, "tail/unroll assumptions");
  constexpr int ASLICE = 128*32*2;  // 8192 B
  constexpr int BSLICE = 256*32*2;  // 16384 B
  constexpr int ATILE = 2*ASLICE;   // 16384 B
  constexpr int BTILE = 2*BSLICE;   // 32768 B
  __shared__ __align__(16) char lds[3*ATILE + 3*BTILE];  // 147456 B

  const int t = threadIdx.x;
  const int lane = t & 63;
  const int w = t >> 6;
  const int wm = w >> 2;
  const int wf = w & 3;
  const int mt = blockIdx.x % NMT;
  const int s  = blockIdx.x / NMT;
  const int k0 = s * CHUNK;

  f32x4_t acc[4][4] = {};

  auto abase = [&](int sl){ return ((sl >> 1) % 3)*ATILE + (sl & 1)*ASLICE; };
  auto bbase = [&](int sl){ return 3*ATILE + ((sl >> 1) % 3)*BTILE + (sl & 1)*BSLICE; };

  auto gllB = [&](int sl){                 // 2 vm instrs
    char* bb = lds + bbase(sl);
    const int kcur = k0 + sl*32;
    const int swzh = ((lane & 3) ^ ((lane >> 2) & 3)) << 3;
    #pragma unroll
    for (int j = 0; j < 2; ++j){
      int chunk = w*2 + j;
      int frow = chunk*16 + (lane >> 2);
      const unsigned short* src = BT + (size_t)frow*KB + kcur + swzh;
      __builtin_amdgcn_global_load_lds((const __attribute__((address_space(1))) void*)src,
                                       (__attribute__((address_space(3))) void*)(bb + chunk*1024),
                                       16, 0, 0);
    }
  };

  auto gllA = [&](int sl){                 // TRANS=0, 1 vm instr
    char* ab = lds + abase(sl);
    const int kcur = k0 + sl*32;
    const int arow = lane >> 2;
    const int kqs  = (lane & 3) ^ (arow & 3);
    const unsigned short* src = Ah + (size_t)(mt*128 + w*16 + arow)*LDA + kcur + kqs*8;
    __builtin_amdgcn_global_load_lds((const __attribute__((address_space(1))) void*)src,
                                     (__attribute__((address_space(3))) void*)(ab + w*1024),
                                     16, 0, 0);
  };

  auto loadA_tr = [&](int sl) -> u32x4 {   // TRANS=1, 1 vm instr
    return *(const u32x4*)(Ah + (size_t)(k0 + sl*32 + (t >> 4))*LDA + mt*128 + (t & 15)*8);
  };

  auto stageA_tr = [&](int sl, u32x4 paw){
    char* ab = lds + abase(sl);
    const int n = t >> 4;
    const int trq = t & 15;
    const bool odd = n & 1;
    const int np = n >> 1;
    uint32 pw[4];
    #pragma unroll
    for (int j = 0; j < 4; ++j) pw[j] = (uint32)__shfl_xor((int)paw[j], 16);
    #pragma unroll
    for (int j = 0; j < 4; ++j){
      int e = trq*8 + 2*j + (odd ? 1 : 0);
      uint32 word = odd ? ((pw[j] >> 16)      | (paw[j] & 0xFFFF0000u))
                        : ((paw[j] & 0xFFFFu) | (pw[j] << 16));
      int pq = (np >> 2) ^ (trq & 3);
      *(uint32*)(ab + e*64 + pq*16 + (np & 3)*4) = word;
    }
  };

  auto compute = [&](int sl){
    const char* ab = lds + abase(sl);
    const char* bb = lds + bbase(sl);
    const int l15 = lane & 15;
    const int kq = lane >> 4;
    bf16x8 af[4], bfr[4];
    #pragma unroll
    for (int mi = 0; mi < 4; ++mi){
      int row = wm*64 + mi*16 + l15;
      int q = TRANS ? (kq ^ ((row >> 3) & 3)) : (kq ^ (row & 3));
      af[mi] = *(const bf16x8*)(ab + row*64 + q*16);
    }
    #pragma unroll
    for (int fi = 0; fi < 4; ++fi){
      int row = wf*64 + fi*16 + l15;
      bfr[fi] = *(const bf16x8*)(bb + row*64 + ((kq ^ (l15 & 3)) << 4));
    }
    #pragma unroll
    for (int mi = 0; mi < 4; ++mi){
      #pragma unroll
      for (int fi = 0; fi < 4; ++fi){
        acc[mi][fi] = __builtin_amdgcn_mfma_f32_16x16x32_bf16(af[mi], bfr[fi], acc[mi][fi], 0, 0, 0);
      }
    }
  };

  if (TRANS){
    // 2-slot (even/odd tile) A-register pipeline, static names.
    u32x4 e0, e1, o0, o1;
    e0 = loadA_tr(0); e1 = loadA_tr(1); gllB(0); gllB(1);   // tile 0
    o0 = loadA_tr(2); o1 = loadA_tr(3); gllB(2); gllB(3);   // tile 1
    stageA_tr(0, e0); stageA_tr(1, e1);                     // auto-waits e-regs
    asm volatile("s_waitcnt vmcnt(6) lgkmcnt(0)" ::: "memory");  // tile0 B done
    __builtin_amdgcn_s_barrier();

    #pragma unroll 1
    for (int T = 0; T < NT - 2; T += 2){
      // phase T (even tile): issue tile T+2 into e-slot; stage tile T+1 from o-slot
      e0 = loadA_tr(2*T + 4); e1 = loadA_tr(2*T + 5);
      gllB(2*T + 4); gllB(2*T + 5);
      compute(2*T); compute(2*T + 1);
      stageA_tr(2*T + 2, o0); stageA_tr(2*T + 3, o1);
      asm volatile("s_waitcnt vmcnt(6) lgkmcnt(0)" ::: "memory");
      __builtin_amdgcn_s_barrier();
      // phase T+1 (odd tile): issue tile T+3 into o-slot; stage tile T+2 from e-slot
      o0 = loadA_tr(2*T + 6); o1 = loadA_tr(2*T + 7);
      gllB(2*T + 6); gllB(2*T + 7);
      compute(2*T + 2); compute(2*T + 3);
      stageA_tr(2*T + 4, e0); stageA_tr(2*T + 5, e1);
      asm volatile("s_waitcnt vmcnt(6) lgkmcnt(0)" ::: "memory");
      __builtin_amdgcn_s_barrier();
    }
    // tail: tile NT-2 (even), then NT-1 (odd, regs in o-slot)
    compute(2*NT - 4); compute(2*NT - 3);
    stageA_tr(2*NT - 2, o0); stageA_tr(2*NT - 1, o1);
    asm volatile("s_waitcnt vmcnt(0) lgkmcnt(0)" ::: "memory");
    __builtin_amdgcn_s_barrier();
    compute(2*NT - 2); compute(2*NT - 1);
  } else {
    gllB(0); gllA(0); gllB(1); gllA(1);   // tile 0 (6 vm)
    gllB(2); gllA(2); gllB(3); gllA(3);   // tile 1 (6 vm)
    asm volatile("s_waitcnt vmcnt(6)" ::: "memory");   // tile0 done
    __builtin_amdgcn_s_barrier();

    #pragma unroll 1
    for (int T = 0; T < NT - 2; ++T){
      gllB(2*T + 4); gllA(2*T + 4); gllB(2*T + 5); gllA(2*T + 5);
      compute(2*T); compute(2*T + 1);
      asm volatile("s_waitcnt vmcnt(6)" ::: "memory");
      __builtin_amdgcn_s_barrier();
    }
    compute(2*NT - 4); compute(2*NT - 3);
    asm volatile("s_waitcnt vmcnt(0)" ::: "memory");
    __builtin_amdgcn_s_barrier();
    compute(2*NT - 2); compute(2*NT - 1);
  }

  // epilogue: bf16 split-K partial
  unsigned short* C = Cp + (size_t)s * (NMT*128) * 256;
  #pragma unroll
  for (int mi = 0; mi < 4; ++mi){
    int row0 = mt*128 + wm*64 + mi*16 + ((lane >> 4) * 4);
    #pragma unroll
    for (int fi = 0; fi < 4; ++fi){
      int f = wf*64 + fi*16 + (lane & 15);
      #pragma unroll
      for (int r = 0; r < 4; ++r)
        C[(size_t)(row0 + r)*256 + f] = f2bf(acc[mi][fi][r]);
    }
  }
}

// ---------------- mid: T1sT[f][e] = bf16( (sum_s bf2f(T1p[s][e][f])) / (de[e]+eps) ) ----------------
__global__ void mid_kernel(const unsigned short* __restrict__ T1p, const float* __restrict__ de,
                           unsigned short* __restrict__ T1sT){
  int f = threadIdx.x;
  int e0 = blockIdx.x * 4;
  float v[4];
  #pragma unroll
  for (int r = 0; r < 4; ++r){
    float acc = 0.f;
    #pragma unroll
    for (int s = 0; s < 8; ++s)
      acc += bfu2f(T1p[(size_t)s*4096*256 + (size_t)(e0 + r)*256 + f]);
    v[r] = acc / (de[e0 + r] + EPSC);
  }
  uint32 lo = pk2(v[0], v[1]);
  uint32 hi = pk2(v[2], v[3]);
  *(u32x2*)(T1sT + (size_t)f*4096 + e0) = u32x2{lo, hi};
}

// ---------------- fin: out[n][f] = relu(dvs[n] * (P0+P1)[n][f]), bf16 partials -> f32 ----------------
__global__ void fin_kernel(const unsigned short* __restrict__ P0, const unsigned short* __restrict__ P1,
                           const float* __restrict__ dvs, float* __restrict__ out){
  int gid = blockIdx.x*256 + threadIdx.x;
  int n = gid >> 5;
  int f0 = (gid & 31) * 8;
  size_t off = (size_t)n*256 + f0;
  u32x4 a = *(const u32x4*)(P0 + off);
  u32x4 b = *(const u32x4*)(P1 + off);
  float d = dvs[n];
  f32x4_t o1, o2;
  #pragma unroll
  for (int j = 0; j < 4; ++j){
    float alo = __builtin_bit_cast(float, a[j] << 16);
    float ahi = __builtin_bit_cast(float, a[j] & 0xFFFF0000u);
    float blo = __builtin_bit_cast(float, b[j] << 16);
    float bhi = __builtin_bit_cast(float, b[j] & 0xFFFF0000u);
    float lo = fmaxf((alo + blo) * d, 0.f);
    float hi = fmaxf((ahi + bhi) * d, 0.f);
    if (j < 2){ o1[2*j] = lo; o1[2*j + 1] = hi; }
    else      { o2[2*(j-2)] = lo; o2[2*(j-2) + 1] = hi; }
  }
  *(f32x4_t*)(out + off) = o1;
  *(f32x4_t*)(out + off + 4) = o2;
}

extern "C" void kernel_launch(void* const* d_in, const int* in_sizes, int n_in,
                              void* d_out, int out_size, void* d_ws, size_t ws_size,
                              hipStream_t stream) {
  const float* emb = (const float*)d_in[0];   // [16384,256]
  const float* H   = (const float*)d_in[1];   // [16384,4096]
  const float* W   = (const float*)d_in[2];   // [256,256]
  float* out = (float*)d_out;                 // f32 [16384,256]

  char* ws = (char*)d_ws;
  float*          dvs       = (float*)(ws + 0);                  //   65536 B
  float*          de        = (float*)(ws + 65536);              //   16384 B
  unsigned short* WT        = (unsigned short*)(ws + 81920);     //  131072 B
  unsigned short* XsT       = (unsigned short*)(ws + 212992);    // 8388608 B  [256][16384] bf16
  unsigned short* T1sT      = (unsigned short*)(ws + 8601600);   // 2097152 B  [256][4096] bf16
  unsigned short* Hb        = (unsigned short*)(ws + 10698752);  // 134217728 B [16384][4096] bf16
  unsigned short* T1p16     = (unsigned short*)(ws + 144916480); // 16777216 B [8][4096][256] bf16
  unsigned short* Op16      = (unsigned short*)(ws + 161693696); // 16777216 B [2][16384][256] bf16
  float*          departial = (float*)(ws + 178470912);          // 4194304 B [256][4096]
  float*          dvpart    = (float*)(ws + 182665216);          // 262144 B [4][16384]
  // total ws usage: 182,927,360 B

  prep_wt<<<256, 256, 0, stream>>>(W, WT);

  // single streaming pass over H: Hb + degree partials
  hdeg_kernel<<<1024, 256, 0, stream>>>(H, dvpart, departial, Hb);
  finish_deg<<<128, 256, 0, stream>>>(dvpart, departial, dvs, de);

  // X: XsT[f][n] = bf16(dvs[n] * (emb@W)[n][f]);  M=16384, K=256
  gemm_x<256, 256, 256, 256><<<256, 256, 0, stream>>>(emb, WT, dvs, XsT);

  // GEMM1: T1p16[s][e][f] = bf16(sum_{n in chunk s} Hb[n][e]*Xs[n][f]);  M=4096 (e), K=16384 (n), split-K=8
  gemm_h<1, 4096, 16384, 32, 2048><<<256, 512, 0, stream>>>(Hb, XsT, T1p16);

  // T1s = De^-1 * sum(T1p16), bf16 transposed
  mid_kernel<<<1024, 256, 0, stream>>>(T1p16, de, T1sT);

  // GEMM2: Op16[s][n][f] = bf16(sum_{e in chunk s} Hb[n][e]*T1s[e][f]);  M=16384 (n), K=4096 (e), split-K=2
  gemm_h<0, 4096, 4096, 128, 2048><<<256, 512, 0, stream>>>(Hb, T1sT, Op16);

  // out = relu(dvs[n] * (Op16_0 + Op16_1))
  fin_kernel<<<2048, 256, 0, stream>>>(Op16, Op16 + (size_t)16384*256, dvs, out);
}